// Round 12
// baseline (138.792 us; speedup 1.0000x reference)
//
#include <hip/hip_runtime.h>
#include <hip/hip_fp8.h>
#include <math.h>

#define SQ2PI_F 0.79788456f

typedef __attribute__((ext_vector_type(8))) short short8;
typedef __attribute__((ext_vector_type(4))) float f32x4;
typedef __attribute__((ext_vector_type(4))) unsigned short u16x4;
typedef __attribute__((address_space(1))) unsigned int gas_u32;
typedef __attribute__((address_space(3))) unsigned int las_u32;

__device__ inline unsigned short bf16rne(float x) {
  unsigned int u = __float_as_uint(x);
  u += 0x7fffu + ((u >> 16) & 1u);
  return (unsigned short)(u >> 16);
}
__device__ inline float bf2f(unsigned short u) {
  return __uint_as_float(((unsigned int)u) << 16);
}
__device__ inline unsigned int pk_fp8x4(f32x4 v) {
  __hip_fp8_e4m3 a(v[0]), b(v[1]), c(v[2]), d(v[3]);
  return (unsigned int)a.__x | ((unsigned int)b.__x << 8) |
         ((unsigned int)c.__x << 16) | ((unsigned int)d.__x << 24);
}
__device__ inline float fp8tof(unsigned char b) {
  __hip_fp8_e4m3 h;
  h.__x = (__hip_fp8_storage_t)b;
  return (float)h;
}

// ------------------------------------------------------------------
// fused prep: means (+bf16/fp8 transposes), zero loss/frac
// ------------------------------------------------------------------
__global__ void k_prep(const float* __restrict__ w0, const float* __restrict__ w1,
                       const float* __restrict__ w2, const float* __restrict__ wlast,
                       float* __restrict__ m0, float* __restrict__ m1,
                       unsigned short* __restrict__ m1th, float* __restrict__ m2,
                       unsigned short* __restrict__ m2th, unsigned char* __restrict__ m2f8,
                       float* __restrict__ mlast, float* __restrict__ lf) {
  int b = blockIdx.x, t = threadIdx.x;
  if (b < 784) {
    int i = b * 256 + t;
    m0[i] = tanhf(0.5f * w0[i]);
  } else if (b < 1040) {
    int j = b - 784;
    float v = tanhf(0.5f * w1[j * 256 + t]);
    m1[j * 256 + t] = v;
    m1th[t * 256 + j] = bf16rne(v);   // m1th[r][k] = m1[k][r]
  } else if (b < 1296) {
    int j = b - 1040;
    float v = tanhf(0.5f * w2[j * 256 + t]);
    m2[j * 256 + t] = v;
    m2th[t * 256 + j] = bf16rne(v);   // m2th[i][j] = m2[j][i]
    m2f8[t * 256 + j] = __hip_fp8_e4m3(v).__x;
  } else {
    int i = (b - 1296) * 256 + t;
    if (i < 2560) mlast[i] = tanhf(0.5f * wlast[i]);
    if (b == 1296 && t < 2) lf[t] = 0.f;
  }
}

// layer 1: block=row r, 512 thr split-k; diagsig1 folded in
__global__ void k_layer1(const float* __restrict__ x, const float* __restrict__ m0,
                         const float* __restrict__ th0,
                         float* __restrict__ x1bar, float* __restrict__ d1) {
  __shared__ float xr[784];
  __shared__ float ph[256], pd[256];
  int r = blockIdx.x, t = threadIdx.x;
  int j = t & 255, h = t >> 8;
  for (int p = t; p < 784; p += 512) xr[p] = x[r * 784 + p];
  __syncthreads();
  float acch = 0.f, accd = 0.f;
  int k0 = h * 392, k1 = k0 + 392;
#pragma unroll 8
  for (int k = k0; k < k1; ++k) {
    float mm = m0[k * 256 + j];
    acch = fmaf(xr[k], mm, acch);
    accd = fmaf(-mm, mm, accd + 1.f);
  }
  if (h) { ph[j] = acch; pd[j] = accd; }
  __syncthreads();
  if (!h) {
    acch += ph[j];
    accd += pd[j];
    float rs = rsqrtf(accd);
    float xb = tanhf(SQ2PI_F * (acch + th0[j]) * rs);
    x1bar[r * 256 + j] = xb;
    d1[r * 256 + j] = 1.f - xb * xb;
  }
}

// layer-2 pass + h3; s1/s2 folded in (block 0 publishes)
__global__ void k_layer2(const float* __restrict__ d1, const float* __restrict__ x1bar,
                         const float* __restrict__ m1, const float* __restrict__ m2,
                         const float* __restrict__ th1, const float* __restrict__ th2,
                         float* __restrict__ c2, float* __restrict__ d2p,
                         float* __restrict__ h3bar,
                         float* __restrict__ s1g, float* __restrict__ s2g) {
  __shared__ float pd[256], ph[256], ps[256], sx[256], p3[256], q2[256];
  int r = blockIdx.x, t = threadIdx.x;
  int i = t & 255, h = t >> 8;
  int j0 = h * 128, j1 = j0 + 128;
  float accd = 0.f, acch = 0.f, accs = 0.f;
  for (int j = j0; j < j1; ++j) {
    float mm = m1[j * 256 + i];
    accd = fmaf(d1[r * 256 + j] * mm, mm, accd);
    acch = fmaf(x1bar[r * 256 + j], mm, acch);
    accs = fmaf(-mm, mm, accs + 1.f);
  }
  if (h) { pd[i] = accd; ph[i] = acch; ps[i] = accs; }
  __syncthreads();
  if (!h) {
    accd += pd[i];
    acch += ph[i];
    accs += ps[i];
    float rs = rsqrtf(accd + accs);
    float xb = tanhf(SQ2PI_F * (acch + th1[i]) * rs);
    float d = 1.f - xb * xb;
    c2[r * 256 + i] = d * rs;
    d2p[r * 256 + i] = d;
    sx[i] = xb;
    if (r == 0) s1g[i] = accs;
  }
  __syncthreads();
  float acc3 = 0.f, acc2 = 0.f;
  for (int j = j0; j < j1; ++j) {
    float mm = m2[j * 256 + i];
    acc3 = fmaf(sx[j], mm, acc3);
    acc2 = fmaf(-mm, mm, acc2 + 1.f);
  }
  if (h) { p3[i] = acc3; q2[i] = acc2; }
  __syncthreads();
  if (!h) {
    h3bar[r * 256 + i] = acc3 + p3[i] + th2[i];
    if (r == 0) s2g[i] = acc2 + q2[i];
  }
}

// ------------------------------------------------------------------
// k_fused: one block (1024 thr / 16 waves) per batch. Wave owns 16 rows.
//   phase 1: xcov2 panels (bf16 MFMA, staged m1th) -> XB exchange -> afX
//   T3 loop: t3 = afX x m2th-panels (bf16 MFMA) -> XC fp8 [l][j] (64KB,
//            XOR-swizzled 8B chunks). XB aliases XC[0..32K) -- lifetimes
//            disjoint (all XB pulls happen >=2 barriers before overwrite).
//   diag:    dsig[l] = sum_j m2th[l][j]*XC[l][j] (row-contiguous reads)
//   c3:      x3bar/c3/d3 (tid<256)
//   SIG:     sigma3 = m2f8 x XC (fp8 MFMA), fused epilogue -> d_out.
//            Barrier-free; 16 waves free-run.
// Per-wave regs: afX 32 / am2f8 16 / acc 8 -> fits 128-reg 16-wave cap.
// MFMA frags: A [row][k] lr=row; B [col][k] lr=col; C rows lk*4+e, cols lr.
// ------------------------------------------------------------------
__global__ __launch_bounds__(1024) void k_fused(
    const unsigned short* __restrict__ m1th, const unsigned short* __restrict__ m2th,
    const unsigned char* __restrict__ m2f8, const float* __restrict__ d1,
    const float* __restrict__ c2, const float* __restrict__ d2p,
    const float* __restrict__ s1, const float* __restrict__ s2,
    const float* __restrict__ h3bar, float* __restrict__ x3bar,
    float* __restrict__ xcov3) {
  __shared__ __align__(16) unsigned char XC[65536];      // t3 fp8 [256][256]
  __shared__ __align__(16) unsigned short SB[2][8192];   // staged weight panels
  __shared__ float c2L[256], d2pL[256], s1L[256], s2L[256];
  __shared__ float c3L[256], d3L[256];
  __shared__ float pq[1024];

  const int b = blockIdx.x;
  const int tid = threadIdx.x;
  const int l = tid & 63, w = tid >> 6;   // 16 waves
  const int lr = l & 15, lk = l >> 4;
  const int R = w * 16;

  // stage one 32x256 bf16 panel (16KB): 1 gload_lds x16B per lane per wave
  auto stage_panel = [&](const unsigned short* gsrc, unsigned short* sb) {
    int rl = w * 2 + (l >> 5);
    int ch = l & 31;
    const unsigned short* src = gsrc + rl * 256 + ((ch ^ (rl & 7)) << 3);
    unsigned short* dst = sb + (w * 2) * 256;
    __builtin_amdgcn_global_load_lds((const gas_u32*)src, (las_u32*)dst, 16, 0, 0);
  };

#define PREAD(SBASE, p, kc)                                   \
  (*(const short8*)((const char*)(SBASE) + ((p) << 9) +      \
                    ((unsigned)((((kc) ^ ((p) & 7))) << 4))))

  stage_panel(m1th, SB[0]);

  if (tid < 256) {
    c2L[tid] = c2[b * 256 + tid];
    d2pL[tid] = d2p[b * 256 + tid];
    s1L[tid] = s1[tid];
    s2L[tid] = s2[tid];
  }

  const float* d1b = d1 + b * 256;

  // hoisted, d1-weighted phase-1 A-frags (wave's 16 rows)
  short8 af_w[8];
#pragma unroll
  for (int ks = 0; ks < 8; ++ks) {
    f32x4 dv0 = *(const f32x4*)(d1b + ks * 32 + lk * 8);
    f32x4 dv1 = *(const f32x4*)(d1b + ks * 32 + lk * 8 + 4);
    short8 mv = *(const short8*)(m1th + (size_t)(R + lr) * 256 + ks * 32 + lk * 8);
#pragma unroll
    for (int e = 0; e < 4; ++e) {
      af_w[ks][e] = (short)bf16rne(bf2f((unsigned short)mv[e]) * dv0[e]);
      af_w[ks][e + 4] = (short)bf16rne(bf2f((unsigned short)mv[e + 4]) * dv1[e]);
    }
  }
  __syncthreads();  // SB[0] staged + c2L visible

  short8 afX[8];  // wave's 16 xcov2 rows
  unsigned short(*XB)[8192] = (unsigned short(*)[8192])XC;  // aliases XC[0..32K)

  // ---------- phase 1: xcov2 panels ----------
#pragma unroll
  for (int cp = 0; cp < 8; ++cp) {
    if (cp < 7)
      stage_panel(m1th + (size_t)(cp + 1) * 8192, SB[(cp + 1) & 1]);
    else
      stage_panel(m2th, SB[0]);  // prologue panel for T3 loop
    const unsigned short* sbc = SB[cp & 1];
    f32x4 acc[2];
    acc[0] = {0.f, 0.f, 0.f, 0.f};
    acc[1] = {0.f, 0.f, 0.f, 0.f};
#pragma unroll
    for (int ks = 0; ks < 8; ++ks) {
      short8 bq0 = PREAD(sbc, lr, ks * 4 + lk);
      short8 bq1 = PREAD(sbc, 16 + lr, ks * 4 + lk);
      acc[0] = __builtin_amdgcn_mfma_f32_16x16x32_bf16(af_w[ks], bq0, acc[0], 0, 0, 0);
      acc[1] = __builtin_amdgcn_mfma_f32_16x16x32_bf16(af_w[ks], bq1, acc[1], 0, 0, 0);
    }
    char* XP = (char*)XB[cp & 1];
    int r0 = R + lk * 4;
#pragma unroll
    for (int j = 0; j < 2; ++j) {
      int p = j * 16 + lr;
      int cc = cp * 32 + p;
      float c2c = c2L[cc];
      u16x4 st;
#pragma unroll
      for (int e = 0; e < 4; ++e) {
        int r = r0 + e;
        float g = acc[j][e];
        if (r == cc) g += s1L[r];
        float v = SQ2PI_F * c2L[r] * c2c * g;
        if (r == cc) v += d2pL[r];
        st[e] = bf16rne(v);
      }
      *(u16x4*)(XP + (p << 9) + (((unsigned)(r0 << 1)) ^ ((p & 7) << 4))) = st;
    }
    __syncthreads();
    if (cp == (w >> 1)) {
      int p2 = (w & 1) * 16 + lr;
#pragma unroll
      for (int ks = 0; ks < 8; ++ks) afX[ks] = PREAD(XP, p2, ks * 4 + lk);
    }
  }

  // ---------- T3 loop: t3 panels -> XC fp8 ----------
#pragma unroll
  for (int lp = 0; lp < 8; ++lp) {
    if (lp < 7) stage_panel(m2th + (size_t)(lp + 1) * 8192, SB[(lp + 1) & 1]);
    const unsigned short* sbt = SB[lp & 1];
    f32x4 at[2];
    at[0] = {0.f, 0.f, 0.f, 0.f};
    at[1] = {0.f, 0.f, 0.f, 0.f};
#pragma unroll
    for (int ks = 0; ks < 8; ++ks) {
      short8 bq0 = PREAD(sbt, lr, ks * 4 + lk);
      short8 bq1 = PREAD(sbt, 16 + lr, ks * 4 + lk);
      at[0] = __builtin_amdgcn_mfma_f32_16x16x32_bf16(afX[ks], bq0, at[0], 0, 0, 0);
      at[1] = __builtin_amdgcn_mfma_f32_16x16x32_bf16(afX[ks], bq1, at[1], 0, 0, 0);
    }
    int j0 = R + lk * 4;
#pragma unroll
    for (int jf = 0; jf < 2; ++jf) {
      int lq = lp * 32 + jf * 16 + lr;
      unsigned int pk = pk_fp8x4(at[jf]);
      *(unsigned int*)(XC + (lq << 8) + ((((j0 >> 3) ^ (lq & 7)) << 3) + (j0 & 7))) = pk;
    }
    __syncthreads();
  }

  // ---------- diag pass: dsig[l] = sum_j m2th[l][j] * t3t[l][j] ----------
  {
    int lq = tid >> 2, q = tid & 3;
    float s = 0.f;
#pragma unroll
    for (int jc = q * 8; jc < q * 8 + 8; ++jc) {
      unsigned long long c8 =
          *(const unsigned long long*)(XC + (lq << 8) + ((jc ^ (lq & 7)) << 3));
      short8 mv = *(const short8*)(m2th + (size_t)lq * 256 + jc * 8);
#pragma unroll
      for (int e = 0; e < 8; ++e)
        s = fmaf(bf2f((unsigned short)mv[e]), fp8tof((unsigned char)(c8 >> (8 * e))), s);
    }
    pq[tid] = s;
  }
  __syncthreads();

  // ---------- c3 phase ----------
  if (tid < 256) {
    float ds = pq[tid * 4] + pq[tid * 4 + 1] + pq[tid * 4 + 2] + pq[tid * 4 + 3] + s2L[tid];
    float rs = rsqrtf(ds);
    float xb = tanhf(SQ2PI_F * h3bar[b * 256 + tid] * rs);
    x3bar[b * 256 + tid] = xb;
    float d = 1.f - xb * xb;
    c3L[tid] = d * rs;
    d3L[tid] = d;
  }
  __syncthreads();

  // ---------- SIG loop: sigma3 (fp8 MFMA) + fused epilogue, barrier-free ----------
  long am2[8];
#pragma unroll
  for (int ks = 0; ks < 8; ++ks)
    am2[ks] = *(const long*)(m2f8 + (size_t)(R + lr) * 256 + ks * 32 + lk * 8);

#pragma unroll
  for (int lp = 0; lp < 8; ++lp) {
    f32x4 sc[2];
    sc[0] = {0.f, 0.f, 0.f, 0.f};
    sc[1] = {0.f, 0.f, 0.f, 0.f};
    int p0 = lp * 32 + lr, p1 = lp * 32 + 16 + lr;
#pragma unroll
    for (int ks = 0; ks < 8; ++ks) {
      long bq0 = *(const long*)(XC + (p0 << 8) + (((ks * 4 + lk) ^ (p0 & 7)) << 3));
      long bq1 = *(const long*)(XC + (p1 << 8) + (((ks * 4 + lk) ^ (p1 & 7)) << 3));
      sc[0] = __builtin_amdgcn_mfma_f32_16x16x32_fp8_fp8(am2[ks], bq0, sc[0], 0, 0, 0);
      sc[1] = __builtin_amdgcn_mfma_f32_16x16x32_fp8_fp8(am2[ks], bq1, sc[1], 0, 0, 0);
    }
    int i0 = R + lk * 4;
#pragma unroll
    for (int lf = 0; lf < 2; ++lf) {
      int gl = lp * 32 + lf * 16 + lr;
      float cg = c3L[gl];
      f32x4 st;
#pragma unroll
      for (int e = 0; e < 4; ++e) {
        int i = i0 + e;
        float g = sc[lf][e];
        if (i == gl) g += s2L[i];
        float v = SQ2PI_F * c3L[i] * cg * g;
        if (i == gl) v += d3L[i];
        st[e] = v;
      }
      *(f32x4*)(xcov3 + ((size_t)b << 16) + (size_t)gl * 256 + i0) = st;
    }
  }
#undef PREAD
}

// final layer + log_softmax + loss + frac_correct. grid 4 x block 64
__global__ void k_final4(const float* __restrict__ x3bar, const float* __restrict__ mlast,
                         const float* __restrict__ thlast, const int* __restrict__ target,
                         float* __restrict__ hlast_out, float* __restrict__ logp_out,
                         float* __restrict__ loss_out, float* __restrict__ frac_out) {
  __shared__ float Wl[2560];
  int t = threadIdx.x;
  int r = blockIdx.x * 64 + t;
  for (int p = t; p < 2560; p += 64) Wl[p] = mlast[p];
  __syncthreads();
  float acc[10];
#pragma unroll
  for (int c = 0; c < 10; ++c) acc[c] = thlast[c];
  for (int j = 0; j < 256; ++j) {
    float xv = x3bar[r * 256 + j];
#pragma unroll
    for (int c = 0; c < 10; ++c) acc[c] = fmaf(xv, Wl[j * 10 + c], acc[c]);
  }
#pragma unroll
  for (int c = 0; c < 10; ++c) hlast_out[r * 10 + c] = acc[c];
  float mx = acc[0];
  int am = 0;
#pragma unroll
  for (int c = 1; c < 10; ++c)
    if (acc[c] > mx) { mx = acc[c]; am = c; }
  float se = 0.f;
#pragma unroll
  for (int c = 0; c < 10; ++c) se += expf(acc[c] - mx);
  float lse = logf(se);
#pragma unroll
  for (int c = 0; c < 10; ++c) logp_out[r * 10 + c] = acc[c] - mx - lse;
  int tg = target[r];
  float lossc = -(acc[tg] - mx - lse) * (1.f / 256.f);
  float corr = (am == tg) ? (1.f / 256.f) : 0.f;
#pragma unroll
  for (int off = 32; off > 0; off >>= 1) {
    lossc += __shfl_down(lossc, off);
    corr += __shfl_down(corr, off);
  }
  if (t == 0) {
    atomicAdd(loss_out, lossc);
    atomicAdd(frac_out, corr);
  }
}

// ------------------------------------------------------------------

extern "C" void kernel_launch(void* const* d_in, const int* in_sizes, int n_in,
                              void* d_out, int out_size, void* d_ws, size_t ws_size,
                              hipStream_t stream) {
  const float* x = (const float*)d_in[0];
  const int* target = (const int*)d_in[1];
  const float* w0 = (const float*)d_in[2];
  const float* w1 = (const float*)d_in[3];
  const float* w2 = (const float*)d_in[4];
  const float* wlast = (const float*)d_in[5];
  const float* th0 = (const float*)d_in[6];
  const float* th1 = (const float*)d_in[7];
  const float* th2 = (const float*)d_in[8];
  const float* thlast = (const float*)d_in[9];

  float* W = (float*)d_ws;
  size_t o = 0;
  auto alloc = [&](size_t n) { float* p = W + o; o += n; return p; };
  float* m0 = alloc(200704);
  float* m1 = alloc(65536);
  float* m2 = alloc(65536);
  float* mlast = alloc(2560);
  float* s1 = alloc(256);
  float* s2 = alloc(256);
  float* x1bar = alloc(65536);
  float* d1 = alloc(65536);
  float* c2 = alloc(65536);
  float* d2p = alloc(65536);
  float* h3bar = alloc(65536);
  float* x3bar = alloc(65536);
  unsigned short* m1th = (unsigned short*)alloc(32768);  // 65536 bf16
  unsigned short* m2th = (unsigned short*)alloc(32768);  // 65536 bf16
  unsigned char* m2f8 = (unsigned char*)alloc(16384);    // 65536 fp8

  float* hlast = (float*)d_out;
  float* logp = hlast + 2560;
  float* xcov3_out = logp + 2560;
  float* loss = xcov3_out + 16777216;
  float* frac = loss + 1;

  // 1) prep (means + transposes + fp8 + zero loss/frac)
  k_prep<<<1306, 256, 0, stream>>>(w0, w1, w2, wlast, m0, m1, m1th, m2, m2th,
                                   m2f8, mlast, loss);
  // 2) layer 1 (split-k, diagsig1 folded)
  k_layer1<<<256, 512, 0, stream>>>(x, m0, th0, x1bar, d1);
  // 3) layer 2 (+h3, s1/s2 folded)
  k_layer2<<<256, 512, 0, stream>>>(d1, x1bar, m1, m2, th1, th2, c2, d2p,
                                    h3bar, s1, s2);
  // 4) fused sigma-chain (16 waves, fp8 t3, no sig persistence)
  k_fused<<<256, 1024, 0, stream>>>(m1th, m2th, m2f8, d1, c2, d2p, s1, s2,
                                    h3bar, x3bar, xcov3_out);
  // 5) final layer + softmax + loss + acc
  k_final4<<<4, 64, 0, stream>>>(x3bar, mlast, thlast, target, hlast, logp, loss, frac);
}

// Round 13
// 138.290 us; speedup vs baseline: 1.0036x; 1.0036x over previous
//
#include <hip/hip_runtime.h>
#include <hip/hip_fp8.h>
#include <math.h>

#define SQ2PI_F 0.79788456f

typedef __attribute__((ext_vector_type(8))) short short8;
typedef __attribute__((ext_vector_type(4))) float f32x4;
typedef __attribute__((ext_vector_type(4))) unsigned short u16x4;
typedef __attribute__((address_space(1))) unsigned int gas_u32;
typedef __attribute__((address_space(3))) unsigned int las_u32;

__device__ inline unsigned short bf16rne(float x) {
  unsigned int u = __float_as_uint(x);
  u += 0x7fffu + ((u >> 16) & 1u);
  return (unsigned short)(u >> 16);
}
__device__ inline float bf2f(unsigned short u) {
  return __uint_as_float(((unsigned int)u) << 16);
}
__device__ inline unsigned int pk_fp8x4(f32x4 v) {
  __hip_fp8_e4m3 a(v[0]), b(v[1]), c(v[2]), d(v[3]);
  return (unsigned int)a.__x | ((unsigned int)b.__x << 8) |
         ((unsigned int)c.__x << 16) | ((unsigned int)d.__x << 24);
}

// ------------------------------------------------------------------
// fused prep: means (+bf16/fp8 transposes), zero loss/frac
// ------------------------------------------------------------------
__global__ void k_prep(const float* __restrict__ w0, const float* __restrict__ w1,
                       const float* __restrict__ w2, const float* __restrict__ wlast,
                       float* __restrict__ m0, float* __restrict__ m1,
                       unsigned short* __restrict__ m1th, float* __restrict__ m2,
                       unsigned short* __restrict__ m2th, unsigned char* __restrict__ m2f8,
                       float* __restrict__ mlast, float* __restrict__ lf) {
  int b = blockIdx.x, t = threadIdx.x;
  if (b < 784) {
    int i = b * 256 + t;
    m0[i] = tanhf(0.5f * w0[i]);
  } else if (b < 1040) {
    int j = b - 784;
    float v = tanhf(0.5f * w1[j * 256 + t]);
    m1[j * 256 + t] = v;
    m1th[t * 256 + j] = bf16rne(v);   // m1th[r][k] = m1[k][r]
  } else if (b < 1296) {
    int j = b - 1040;
    float v = tanhf(0.5f * w2[j * 256 + t]);
    m2[j * 256 + t] = v;
    m2th[t * 256 + j] = bf16rne(v);   // m2th[i][j] = m2[j][i]
    m2f8[t * 256 + j] = __hip_fp8_e4m3(v).__x;
  } else {
    int i = (b - 1296) * 256 + t;
    if (i < 2560) mlast[i] = tanhf(0.5f * wlast[i]);
    if (b == 1296 && t < 2) lf[t] = 0.f;
  }
}

// layer 1: block=row r, 512 thr split-k; diagsig1 folded in
__global__ void k_layer1(const float* __restrict__ x, const float* __restrict__ m0,
                         const float* __restrict__ th0,
                         float* __restrict__ x1bar, float* __restrict__ d1) {
  __shared__ float xr[784];
  __shared__ float ph[256], pd[256];
  int r = blockIdx.x, t = threadIdx.x;
  int j = t & 255, h = t >> 8;
  for (int p = t; p < 784; p += 512) xr[p] = x[r * 784 + p];
  __syncthreads();
  float acch = 0.f, accd = 0.f;
  int k0 = h * 392, k1 = k0 + 392;
#pragma unroll 8
  for (int k = k0; k < k1; ++k) {
    float mm = m0[k * 256 + j];
    acch = fmaf(xr[k], mm, acch);
    accd = fmaf(-mm, mm, accd + 1.f);
  }
  if (h) { ph[j] = acch; pd[j] = accd; }
  __syncthreads();
  if (!h) {
    acch += ph[j];
    accd += pd[j];
    float rs = rsqrtf(accd);
    float xb = tanhf(SQ2PI_F * (acch + th0[j]) * rs);
    x1bar[r * 256 + j] = xb;
    d1[r * 256 + j] = 1.f - xb * xb;
  }
}

// layer-2 pass + h3; s1/s2 folded in (block 0 publishes)
__global__ void k_layer2(const float* __restrict__ d1, const float* __restrict__ x1bar,
                         const float* __restrict__ m1, const float* __restrict__ m2,
                         const float* __restrict__ th1, const float* __restrict__ th2,
                         float* __restrict__ c2, float* __restrict__ d2p,
                         float* __restrict__ h3bar,
                         float* __restrict__ s1g, float* __restrict__ s2g) {
  __shared__ float pd[256], ph[256], ps[256], sx[256], p3[256], q2[256];
  int r = blockIdx.x, t = threadIdx.x;
  int i = t & 255, h = t >> 8;
  int j0 = h * 128, j1 = j0 + 128;
  float accd = 0.f, acch = 0.f, accs = 0.f;
  for (int j = j0; j < j1; ++j) {
    float mm = m1[j * 256 + i];
    accd = fmaf(d1[r * 256 + j] * mm, mm, accd);
    acch = fmaf(x1bar[r * 256 + j], mm, acch);
    accs = fmaf(-mm, mm, accs + 1.f);
  }
  if (h) { pd[i] = accd; ph[i] = acch; ps[i] = accs; }
  __syncthreads();
  if (!h) {
    accd += pd[i];
    acch += ph[i];
    accs += ps[i];
    float rs = rsqrtf(accd + accs);
    float xb = tanhf(SQ2PI_F * (acch + th1[i]) * rs);
    float d = 1.f - xb * xb;
    c2[r * 256 + i] = d * rs;
    d2p[r * 256 + i] = d;
    sx[i] = xb;
    if (r == 0) s1g[i] = accs;
  }
  __syncthreads();
  float acc3 = 0.f, acc2 = 0.f;
  for (int j = j0; j < j1; ++j) {
    float mm = m2[j * 256 + i];
    acc3 = fmaf(sx[j], mm, acc3);
    acc2 = fmaf(-mm, mm, acc2 + 1.f);
  }
  if (h) { p3[i] = acc3; q2[i] = acc2; }
  __syncthreads();
  if (!h) {
    h3bar[r * 256 + i] = acc3 + p3[i] + th2[i];
    if (r == 0) s2g[i] = acc2 + q2[i];
  }
}

// ------------------------------------------------------------------
// k_fused: one block (1024 thr / 16 waves, __launch_bounds__(1024,4) ->
// 128-VGPR budget, no spill) per batch. Wave owns 16 output rows.
//   phase 1 (4 x 64-col segments): xcov2 = af_w x m1th-panel (bf16 MFMA,
//     gload_lds-staged SB dbuf) -> XB exchange -> afX regs.
//   T3 (4 x 64-col segments): t3 = afX x m2th-panel -> XC fp8 (264B-padded
//     rows, conflict-free); diag partials folded into epilogue (m2th read
//     from the staged SB panel; shfl over lk + LDS atomicAdd).
//   c3 phase, then SIG loop (barrier-free): sigma3 = m2f8 x XC (fp8 MFMA),
//     fused epilogue -> fp32 d_out.
// XB (2x32KB) aliases XC (67.6KB): lifetimes disjoint (pull at cp==w>>2
// directly after that segment's barrier; T3's per-segment barriers order
// all reuse -- safety argument in round-13 notes).
// MFMA frags: A [row][k] lr=row; B [col][k] lr=col; C rows lk*4+e, cols lr.
// ------------------------------------------------------------------
__global__ __launch_bounds__(1024, 4) void k_fused(
    const unsigned short* __restrict__ m1th, const unsigned short* __restrict__ m2th,
    const unsigned char* __restrict__ m2f8, const float* __restrict__ d1,
    const float* __restrict__ c2, const float* __restrict__ d2p,
    const float* __restrict__ s1, const float* __restrict__ s2,
    const float* __restrict__ h3bar, float* __restrict__ x3bar,
    float* __restrict__ xcov3) {
  __shared__ __align__(16) unsigned char XC[67584];      // t3 fp8 [256][264B]
  __shared__ __align__(16) unsigned short SB[2][16384];  // staged 64-col panels
  __shared__ float c2L[256], d2pL[256], s1L[256], s2L[256];
  __shared__ float dsig[256], c3L[256], d3L[256];

  const int b = blockIdx.x;
  const int tid = threadIdx.x;
  const int l = tid & 63, w = tid >> 6;   // 16 waves
  const int lr = l & 15, lk = l >> 4;
  const int R = w * 16;

  // stage one 64x256 bf16 panel (32KB): 2 gload_lds x16B per lane
  auto stage_panel = [&](const unsigned short* gsrc, unsigned short* sb) {
#pragma unroll
    for (int q = 0; q < 2; ++q) {
      int rl = q * 32 + w * 2 + (l >> 5);
      int ch = l & 31;
      const unsigned short* src = gsrc + rl * 256 + ((ch ^ (rl & 7)) << 3);
      unsigned short* dst = sb + (q * 32 + w * 2) * 256;
      __builtin_amdgcn_global_load_lds((const gas_u32*)src, (las_u32*)dst, 16, 0, 0);
    }
  };

#define PREAD(SBASE, p, kc)                                   \
  (*(const short8*)((const char*)(SBASE) + ((p) << 9) +      \
                    ((unsigned)((((kc) ^ ((p) & 7))) << 4))))

  stage_panel(m1th, SB[0]);

  if (tid < 256) {
    c2L[tid] = c2[b * 256 + tid];
    d2pL[tid] = d2p[b * 256 + tid];
    s1L[tid] = s1[tid];
    s2L[tid] = s2[tid];
    dsig[tid] = 0.f;
  }

  const float* d1b = d1 + b * 256;

  // hoisted, d1-weighted phase-1 A-frags (wave's 16 rows)
  short8 af_w[8];
#pragma unroll
  for (int ks = 0; ks < 8; ++ks) {
    f32x4 dv0 = *(const f32x4*)(d1b + ks * 32 + lk * 8);
    f32x4 dv1 = *(const f32x4*)(d1b + ks * 32 + lk * 8 + 4);
    short8 mv = *(const short8*)(m1th + (size_t)(R + lr) * 256 + ks * 32 + lk * 8);
#pragma unroll
    for (int e = 0; e < 4; ++e) {
      af_w[ks][e] = (short)bf16rne(bf2f((unsigned short)mv[e]) * dv0[e]);
      af_w[ks][e + 4] = (short)bf16rne(bf2f((unsigned short)mv[e + 4]) * dv1[e]);
    }
  }
  __syncthreads();  // SB[0] staged + LDS vectors visible

  short8 afX[8];  // wave's 16 xcov2 rows
  unsigned short(*XB)[16384] = (unsigned short(*)[16384])XC;  // aliases XC

  // ---------- phase 1: xcov2, 4 segments of 64 cols ----------
#pragma unroll
  for (int cp = 0; cp < 4; ++cp) {
    if (cp < 3)
      stage_panel(m1th + (size_t)(cp + 1) * 16384, SB[(cp + 1) & 1]);
    else
      stage_panel(m2th, SB[0]);  // prologue panel for T3
    const unsigned short* sbc = SB[cp & 1];
    f32x4 acc[4];
#pragma unroll
    for (int j = 0; j < 4; ++j) acc[j] = {0.f, 0.f, 0.f, 0.f};
#pragma unroll
    for (int ks = 0; ks < 8; ++ks) {
#pragma unroll
      for (int j = 0; j < 4; ++j) {
        short8 bq = PREAD(sbc, j * 16 + lr, ks * 4 + lk);
        acc[j] = __builtin_amdgcn_mfma_f32_16x16x32_bf16(af_w[ks], bq, acc[j], 0, 0, 0);
      }
    }
    char* XP = (char*)XB[cp & 1];
    int r0 = R + lk * 4;
#pragma unroll
    for (int j = 0; j < 4; ++j) {
      int p = j * 16 + lr;
      int cc = cp * 64 + p;
      float c2c = c2L[cc];
      u16x4 st;
#pragma unroll
      for (int e = 0; e < 4; ++e) {
        int r = r0 + e;
        float g = acc[j][e];
        if (r == cc) g += s1L[r];
        float v = SQ2PI_F * c2L[r] * c2c * g;
        if (r == cc) v += d2pL[r];
        st[e] = bf16rne(v);
      }
      *(u16x4*)(XP + (p << 9) + (((unsigned)(r0 << 1)) ^ ((p & 7) << 4))) = st;
    }
    __syncthreads();
    if (cp == (w >> 2)) {
      int p2 = (w & 3) * 16 + lr;
#pragma unroll
      for (int ks = 0; ks < 8; ++ks) afX[ks] = PREAD(XP, p2, ks * 4 + lk);
    }
  }

  // ---------- T3: 4 segments of 64 cols; fp8 store + fused diag ----------
#pragma unroll
  for (int lp = 0; lp < 4; ++lp) {
    if (lp < 3) stage_panel(m2th + (size_t)(lp + 1) * 16384, SB[(lp + 1) & 1]);
    const unsigned short* sbt = SB[lp & 1];
    f32x4 at[4];
#pragma unroll
    for (int j = 0; j < 4; ++j) at[j] = {0.f, 0.f, 0.f, 0.f};
#pragma unroll
    for (int ks = 0; ks < 8; ++ks) {
#pragma unroll
      for (int j = 0; j < 4; ++j) {
        short8 bq = PREAD(sbt, j * 16 + lr, ks * 4 + lk);
        at[j] = __builtin_amdgcn_mfma_f32_16x16x32_bf16(afX[ks], bq, at[j], 0, 0, 0);
      }
    }
    int j0 = R + lk * 4;
#pragma unroll
    for (int jf = 0; jf < 4; ++jf) {
      int p = jf * 16 + lr;       // row within panel
      int lq = lp * 64 + p;       // global t3 column
      // fp8 pack -> XC (padded 264B rows, conflict-free)
      *(unsigned int*)(XC + (size_t)lq * 264 + j0) = pk_fp8x4(at[jf]);
      // diag partial: m2th[lq][j0..j0+3] from staged panel (pre-rounding t3)
      const char* mb = (const char*)sbt + (p << 9) +
                       ((((j0 >> 3) ^ (p & 7))) << 4) + ((j0 & 7) << 1);
      u16x4 mv = *(const u16x4*)mb;
      float s = 0.f;
#pragma unroll
      for (int e = 0; e < 4; ++e) s = fmaf(bf2f(mv[e]), at[jf][e], s);
      s += __shfl_xor(s, 16, 64);
      s += __shfl_xor(s, 32, 64);
      if (lk == 0) atomicAdd(&dsig[lq], s);
    }
    __syncthreads();
  }

  // ---------- c3 phase ----------
  if (tid < 256) {
    float ds = dsig[tid] + s2L[tid];
    float rs = rsqrtf(ds);
    float xb = tanhf(SQ2PI_F * h3bar[b * 256 + tid] * rs);
    x3bar[b * 256 + tid] = xb;
    float d = 1.f - xb * xb;
    c3L[tid] = d * rs;
    d3L[tid] = d;
  }
  __syncthreads();

  // ---------- SIG loop: sigma3 (fp8 MFMA) + fused epilogue, barrier-free ----------
  long am2[8];
#pragma unroll
  for (int ks = 0; ks < 8; ++ks)
    am2[ks] = *(const long*)(m2f8 + (size_t)(R + lr) * 256 + ks * 32 + lk * 8);

#pragma unroll
  for (int lp = 0; lp < 4; ++lp) {
    f32x4 sc[4];
#pragma unroll
    for (int j = 0; j < 4; ++j) sc[j] = {0.f, 0.f, 0.f, 0.f};
#pragma unroll
    for (int ks = 0; ks < 8; ++ks) {
#pragma unroll
      for (int j = 0; j < 4; ++j) {
        int p = lp * 64 + j * 16 + lr;
        long bq = *(const long*)(XC + (size_t)p * 264 + (ks * 4 + lk) * 8);
        sc[j] = __builtin_amdgcn_mfma_f32_16x16x32_fp8_fp8(am2[ks], bq, sc[j], 0, 0, 0);
      }
    }
    int i0 = R + lk * 4;
#pragma unroll
    for (int lf = 0; lf < 4; ++lf) {
      int gl = lp * 64 + lf * 16 + lr;
      float cg = c3L[gl];
      f32x4 st;
#pragma unroll
      for (int e = 0; e < 4; ++e) {
        int i = i0 + e;
        float g = sc[lf][e];
        if (i == gl) g += s2L[i];
        float v = SQ2PI_F * c3L[i] * cg * g;
        if (i == gl) v += d3L[i];
        st[e] = v;
      }
      *(f32x4*)(xcov3 + ((size_t)b << 16) + (size_t)gl * 256 + i0) = st;
    }
  }
#undef PREAD
}

// final layer + log_softmax + loss + frac_correct. grid 4 x block 64
__global__ void k_final4(const float* __restrict__ x3bar, const float* __restrict__ mlast,
                         const float* __restrict__ thlast, const int* __restrict__ target,
                         float* __restrict__ hlast_out, float* __restrict__ logp_out,
                         float* __restrict__ loss_out, float* __restrict__ frac_out) {
  __shared__ float Wl[2560];
  int t = threadIdx.x;
  int r = blockIdx.x * 64 + t;
  for (int p = t; p < 2560; p += 64) Wl[p] = mlast[p];
  __syncthreads();
  float acc[10];
#pragma unroll
  for (int c = 0; c < 10; ++c) acc[c] = thlast[c];
  for (int j = 0; j < 256; ++j) {
    float xv = x3bar[r * 256 + j];
#pragma unroll
    for (int c = 0; c < 10; ++c) acc[c] = fmaf(xv, Wl[j * 10 + c], acc[c]);
  }
#pragma unroll
  for (int c = 0; c < 10; ++c) hlast_out[r * 10 + c] = acc[c];
  float mx = acc[0];
  int am = 0;
#pragma unroll
  for (int c = 1; c < 10; ++c)
    if (acc[c] > mx) { mx = acc[c]; am = c; }
  float se = 0.f;
#pragma unroll
  for (int c = 0; c < 10; ++c) se += expf(acc[c] - mx);
  float lse = logf(se);
#pragma unroll
  for (int c = 0; c < 10; ++c) logp_out[r * 10 + c] = acc[c] - mx - lse;
  int tg = target[r];
  float lossc = -(acc[tg] - mx - lse) * (1.f / 256.f);
  float corr = (am == tg) ? (1.f / 256.f) : 0.f;
#pragma unroll
  for (int off = 32; off > 0; off >>= 1) {
    lossc += __shfl_down(lossc, off);
    corr += __shfl_down(corr, off);
  }
  if (t == 0) {
    atomicAdd(loss_out, lossc);
    atomicAdd(frac_out, corr);
  }
}

// ------------------------------------------------------------------

extern "C" void kernel_launch(void* const* d_in, const int* in_sizes, int n_in,
                              void* d_out, int out_size, void* d_ws, size_t ws_size,
                              hipStream_t stream) {
  const float* x = (const float*)d_in[0];
  const int* target = (const int*)d_in[1];
  const float* w0 = (const float*)d_in[2];
  const float* w1 = (const float*)d_in[3];
  const float* w2 = (const float*)d_in[4];
  const float* wlast = (const float*)d_in[5];
  const float* th0 = (const float*)d_in[6];
  const float* th1 = (const float*)d_in[7];
  const float* th2 = (const float*)d_in[8];
  const float* thlast = (const float*)d_in[9];

  float* W = (float*)d_ws;
  size_t o = 0;
  auto alloc = [&](size_t n) { float* p = W + o; o += n; return p; };
  float* m0 = alloc(200704);
  float* m1 = alloc(65536);
  float* m2 = alloc(65536);
  float* mlast = alloc(2560);
  float* s1 = alloc(256);
  float* s2 = alloc(256);
  float* x1bar = alloc(65536);
  float* d1 = alloc(65536);
  float* c2 = alloc(65536);
  float* d2p = alloc(65536);
  float* h3bar = alloc(65536);
  float* x3bar = alloc(65536);
  unsigned short* m1th = (unsigned short*)alloc(32768);  // 65536 bf16
  unsigned short* m2th = (unsigned short*)alloc(32768);  // 65536 bf16
  unsigned char* m2f8 = (unsigned char*)alloc(16384);    // 65536 fp8

  float* hlast = (float*)d_out;
  float* logp = hlast + 2560;
  float* xcov3_out = logp + 2560;
  float* loss = xcov3_out + 16777216;
  float* frac = loss + 1;

  // 1) prep (means + transposes + fp8 + zero loss/frac)
  k_prep<<<1306, 256, 0, stream>>>(w0, w1, w2, wlast, m0, m1, m1th, m2, m2th,
                                   m2f8, mlast, loss);
  // 2) layer 1 (split-k, diagsig1 folded)
  k_layer1<<<256, 512, 0, stream>>>(x, m0, th0, x1bar, d1);
  // 3) layer 2 (+h3, s1/s2 folded)
  k_layer2<<<256, 512, 0, stream>>>(d1, x1bar, m1, m2, th1, th2, c2, d2p,
                                    h3bar, s1, s2);
  // 4) fused sigma-chain (16 waves @128 VGPR, padded XC, fused diag)
  k_fused<<<256, 1024, 0, stream>>>(m1th, m2th, m2f8, d1, c2, d2p, s1, s2,
                                    h3bar, x3bar, xcov3_out);
  // 5) final layer + softmax + loss + acc
  k_final4<<<4, 64, 0, stream>>>(x3bar, mlast, thlast, target, hlast, logp, loss, frac);
}

// Round 14
// 135.001 us; speedup vs baseline: 1.0281x; 1.0244x over previous
//
#include <hip/hip_runtime.h>
#include <hip/hip_fp8.h>
#include <math.h>

#define SQ2PI_F 0.79788456f

typedef __attribute__((ext_vector_type(4))) float f32x4;
typedef __attribute__((address_space(1))) unsigned int gas_u32;
typedef __attribute__((address_space(3))) unsigned int las_u32;

__device__ inline unsigned short bf16rne(float x) {
  unsigned int u = __float_as_uint(x);
  u += 0x7fffu + ((u >> 16) & 1u);
  return (unsigned short)(u >> 16);
}
__device__ inline unsigned char f2fp8(float v) { return __hip_fp8_e4m3(v).__x; }
__device__ inline float fp8tof(unsigned char b) {
  __hip_fp8_e4m3 h;
  h.__x = (__hip_fp8_storage_t)b;
  return (float)h;
}
__device__ inline unsigned int pk_fp8x4(f32x4 v) {
  return (unsigned int)f2fp8(v[0]) | ((unsigned int)f2fp8(v[1]) << 8) |
         ((unsigned int)f2fp8(v[2]) << 16) | ((unsigned int)f2fp8(v[3]) << 24);
}

// ------------------------------------------------------------------
// prep: means + fp8 transposes; zero loss/frac
// ------------------------------------------------------------------
__global__ void k_prep(const float* __restrict__ w0, const float* __restrict__ w1,
                       const float* __restrict__ w2, const float* __restrict__ wlast,
                       float* __restrict__ m0, float* __restrict__ m1,
                       unsigned char* __restrict__ m1f8t, float* __restrict__ m2,
                       unsigned char* __restrict__ m2f8, float* __restrict__ mlast,
                       float* __restrict__ lf) {
  int b = blockIdx.x, t = threadIdx.x;
  if (b < 784) {
    int i = b * 256 + t;
    m0[i] = tanhf(0.5f * w0[i]);
  } else if (b < 1040) {
    int j = b - 784;
    float v = tanhf(0.5f * w1[j * 256 + t]);
    m1[j * 256 + t] = v;
    m1f8t[t * 256 + j] = f2fp8(v);    // m1f8t[r][k] = m1[k][r]
  } else if (b < 1296) {
    int j = b - 1040;
    float v = tanhf(0.5f * w2[j * 256 + t]);
    m2[j * 256 + t] = v;
    m2f8[t * 256 + j] = f2fp8(v);     // m2f8[i][j] = m2[j][i]
  } else {
    int i = (b - 1296) * 256 + t;
    if (i < 2560) mlast[i] = tanhf(0.5f * wlast[i]);
    if (b == 1296 && t < 2) lf[t] = 0.f;
  }
}

// layer 1: block=row r, 512 thr split-k; diagsig1 folded in
__global__ void k_layer1(const float* __restrict__ x, const float* __restrict__ m0,
                         const float* __restrict__ th0,
                         float* __restrict__ x1bar, float* __restrict__ d1) {
  __shared__ float xr[784];
  __shared__ float ph[256], pd[256];
  int r = blockIdx.x, t = threadIdx.x;
  int j = t & 255, h = t >> 8;
  for (int p = t; p < 784; p += 512) xr[p] = x[r * 784 + p];
  __syncthreads();
  float acch = 0.f, accd = 0.f;
  int k0 = h * 392, k1 = k0 + 392;
#pragma unroll 8
  for (int k = k0; k < k1; ++k) {
    float mm = m0[k * 256 + j];
    acch = fmaf(xr[k], mm, acch);
    accd = fmaf(-mm, mm, accd + 1.f);
  }
  if (h) { ph[j] = acch; pd[j] = accd; }
  __syncthreads();
  if (!h) {
    acch += ph[j];
    accd += pd[j];
    float rs = rsqrtf(accd);
    float xb = tanhf(SQ2PI_F * (acch + th0[j]) * rs);
    x1bar[r * 256 + j] = xb;
    d1[r * 256 + j] = 1.f - xb * xb;
  }
}

// layer-2 pass + h3; s1/s2 folded in (block 0 publishes)
__global__ void k_layer2(const float* __restrict__ d1, const float* __restrict__ x1bar,
                         const float* __restrict__ m1, const float* __restrict__ m2,
                         const float* __restrict__ th1, const float* __restrict__ th2,
                         float* __restrict__ c2, float* __restrict__ d2p,
                         float* __restrict__ h3bar,
                         float* __restrict__ s1g, float* __restrict__ s2g) {
  __shared__ float pd[256], ph[256], ps[256], sx[256], p3[256], q2[256];
  int r = blockIdx.x, t = threadIdx.x;
  int i = t & 255, h = t >> 8;
  int j0 = h * 128, j1 = j0 + 128;
  float accd = 0.f, acch = 0.f, accs = 0.f;
  for (int j = j0; j < j1; ++j) {
    float mm = m1[j * 256 + i];
    accd = fmaf(d1[r * 256 + j] * mm, mm, accd);
    acch = fmaf(x1bar[r * 256 + j], mm, acch);
    accs = fmaf(-mm, mm, accs + 1.f);
  }
  if (h) { pd[i] = accd; ph[i] = acch; ps[i] = accs; }
  __syncthreads();
  if (!h) {
    accd += pd[i];
    acch += ph[i];
    accs += ps[i];
    float rs = rsqrtf(accd + accs);
    float xb = tanhf(SQ2PI_F * (acch + th1[i]) * rs);
    float d = 1.f - xb * xb;
    c2[r * 256 + i] = d * rs;
    d2p[r * 256 + i] = d;
    sx[i] = xb;
    if (r == 0) s1g[i] = accs;
  }
  __syncthreads();
  float acc3 = 0.f, acc2 = 0.f;
  for (int j = j0; j < j1; ++j) {
    float mm = m2[j * 256 + i];
    acc3 = fmaf(sx[j], mm, acc3);
    acc2 = fmaf(-mm, mm, acc2 + 1.f);
  }
  if (h) { p3[i] = acc3; q2[i] = acc2; }
  __syncthreads();
  if (!h) {
    h3bar[r * 256 + i] = acc3 + p3[i] + th2[i];
    if (r == 0) s2g[i] = acc2 + q2[i];
  }
}

// ------------------------------------------------------------------
// k_fused (full fp8 operands): 1024 thr / 16 waves per batch, wave owns
// 16 output rows. fp8 frags are `long` (2 VGPR) -> per-wave arch state
// ~50 regs -> fits the 64-arch + 64-acc unified split at 4 waves/SIMD
// (no spill; rounds 10-13's 20-25MB scratch traffic eliminated).
//   phase 1 (4 x 64-col segs): xcov2 = af_w(fp8,d1-weighted) x m1f8t
//     panel (fp8 MFMA) -> XB exchange (fp8) -> afX (8 longs).
//   T3 (4 segs): t3 = afX x m2f8-panel -> XC fp8 (264B-padded rows);
//     diag partials from staged fp8 m2 + pre-rounding f32 t3.
//   c3 phase; SIG loop (barrier-free): sigma3 = am2 x XC, epilogue -> out.
// Panel swizzle: 8B granule pos = kc ^ ((p&7)<<1); gload source 16B chunk
// = c ^ (p&7) (chunk-consistent with the granule XOR; <=2-way banks).
// MFMA frags (fp8 16x16x32): A[row=lr][k:lk*8+..], B[col=lr][k:lk*8+..],
// C rows lk*4+e, cols lr  (HW-validated by r12/13's passing SIG loop).
// ------------------------------------------------------------------
__global__ __launch_bounds__(1024, 4) void k_fused(
    const unsigned char* __restrict__ m1f8t, const unsigned char* __restrict__ m2f8,
    const float* __restrict__ d1, const float* __restrict__ c2,
    const float* __restrict__ d2p, const float* __restrict__ s1,
    const float* __restrict__ s2, const float* __restrict__ h3bar,
    float* __restrict__ x3bar, float* __restrict__ xcov3) {
  __shared__ __align__(16) unsigned char XC[67584];     // t3 fp8 [256][264B]
  __shared__ __align__(16) unsigned char SB[2][16384];  // staged fp8 panels
  __shared__ __align__(16) unsigned char XB[2][16384];  // xcov2 fp8 exchange
  __shared__ float c2L[256], d2pL[256], s1L[256], s2L[256];
  __shared__ float dsig[256], c3L[256], d3L[256];

  const int b = blockIdx.x;
  const int tid = threadIdx.x;
  const int l = tid & 63, w = tid >> 6;  // 16 waves
  const int lr = l & 15, lk = l >> 4;
  const int R = w * 16;

  // stage one 64x256 fp8 panel (16KB): 1 gload_lds x16B per lane
  auto stage_f8 = [&](const unsigned char* gsrc, unsigned char* sb) {
    int rl = w * 4 + (l >> 4);
    int c = l & 15;
    const unsigned char* src = gsrc + rl * 256 + ((c ^ (rl & 7)) << 4);
    unsigned char* dst = sb + w * 1024;  // wave-uniform; +lane*16 by HW
    __builtin_amdgcn_global_load_lds((const gas_u32*)src, (las_u32*)dst, 16, 0, 0);
  };

// read logical 8B granule kc (0..31) at panel row p (0..63)
#define PRD8(S, p, kc) \
  (*(const long*)((const unsigned char*)(S) + ((p) << 8) + ((((kc) ^ (((p) & 7) << 1))) << 3)))

  stage_f8(m1f8t, SB[0]);

  if (tid < 256) {
    c2L[tid] = c2[b * 256 + tid];
    d2pL[tid] = d2p[b * 256 + tid];
    s1L[tid] = s1[tid];
    s2L[tid] = s2[tid];
    dsig[tid] = 0.f;
  }

  const float* d1b = d1 + b * 256;

  // hoisted, d1-weighted phase-1 A-frags (fp8, wave's 16 rows)
  long af_w[8];
#pragma unroll
  for (int ks = 0; ks < 8; ++ks) {
    unsigned long long mr =
        *(const unsigned long long*)(m1f8t + (size_t)(R + lr) * 256 + ks * 32 + lk * 8);
    const float* dp = d1b + ks * 32 + lk * 8;
    unsigned long long out = 0;
#pragma unroll
    for (int e = 0; e < 8; ++e) {
      float v = fp8tof((unsigned char)(mr >> (8 * e))) * dp[e];
      out |= ((unsigned long long)f2fp8(v)) << (8 * e);
    }
    af_w[ks] = (long)out;
  }
  __syncthreads();  // SB[0] staged + LDS vectors visible

  long afX[8];  // wave's 16 xcov2 rows (fp8 A-frags)

  // ---------- phase 1: xcov2, 4 segments of 64 cols ----------
#pragma unroll
  for (int cp = 0; cp < 4; ++cp) {
    if (cp < 3)
      stage_f8(m1f8t + (size_t)(cp + 1) * 16384, SB[(cp + 1) & 1]);
    else
      stage_f8(m2f8, SB[0]);  // prologue panel for T3
    const unsigned char* sbc = SB[cp & 1];
    f32x4 acc[4];
#pragma unroll
    for (int j = 0; j < 4; ++j) acc[j] = {0.f, 0.f, 0.f, 0.f};
#pragma unroll
    for (int ks = 0; ks < 8; ++ks) {
#pragma unroll
      for (int j = 0; j < 4; ++j) {
        long bq = PRD8(sbc, j * 16 + lr, ks * 4 + lk);
        acc[j] = __builtin_amdgcn_mfma_f32_16x16x32_fp8_fp8(af_w[ks], bq, acc[j], 0, 0, 0);
      }
    }
    unsigned char* XP = XB[cp & 1];
    int r0 = R + lk * 4;
#pragma unroll
    for (int j = 0; j < 4; ++j) {
      int p = j * 16 + lr;
      int cc = cp * 64 + p;
      float c2c = c2L[cc];
      f32x4 st;
#pragma unroll
      for (int e = 0; e < 4; ++e) {
        int r = r0 + e;
        float g = acc[j][e];
        if (r == cc) g += s1L[r];
        float v = SQ2PI_F * c2L[r] * c2c * g;
        if (r == cc) v += d2pL[r];
        st[e] = v;
      }
      // transposed-symmetric fp8 store: XB[p][logical bytes r0..r0+3]
      *(unsigned int*)(XP + (p << 8) + ((((r0 >> 3) ^ ((p & 7) << 1))) << 3) + (r0 & 7)) =
          pk_fp8x4(st);
    }
    __syncthreads();
    if (cp == (w >> 2)) {
      int p2 = (w & 3) * 16 + lr;
#pragma unroll
      for (int ks = 0; ks < 8; ++ks) afX[ks] = PRD8(XP, p2, ks * 4 + lk);
    }
  }

  // ---------- T3: 4 segments; fp8 XC store + fused diag ----------
#pragma unroll
  for (int lp = 0; lp < 4; ++lp) {
    if (lp < 3) stage_f8(m2f8 + (size_t)(lp + 1) * 16384, SB[(lp + 1) & 1]);
    const unsigned char* sbt = SB[lp & 1];
    f32x4 at[4];
#pragma unroll
    for (int j = 0; j < 4; ++j) at[j] = {0.f, 0.f, 0.f, 0.f};
#pragma unroll
    for (int ks = 0; ks < 8; ++ks) {
#pragma unroll
      for (int j = 0; j < 4; ++j) {
        long bq = PRD8(sbt, j * 16 + lr, ks * 4 + lk);
        at[j] = __builtin_amdgcn_mfma_f32_16x16x32_fp8_fp8(afX[ks], bq, at[j], 0, 0, 0);
      }
    }
    int j0 = R + lk * 4;
#pragma unroll
    for (int jf = 0; jf < 4; ++jf) {
      int p = jf * 16 + lr;   // row within panel
      int lq = lp * 64 + p;   // global t3 column
      *(unsigned int*)(XC + (size_t)lq * 264 + j0) = pk_fp8x4(at[jf]);
      // diag partial: m2t[lq][j0..j0+3] from staged fp8 panel, f32 t3
      unsigned int mraw = *(const unsigned int*)(
          sbt + (p << 8) + ((((j0 >> 3) ^ ((p & 7) << 1))) << 3) + (j0 & 7));
      float s = 0.f;
#pragma unroll
      for (int e = 0; e < 4; ++e)
        s = fmaf(fp8tof((unsigned char)(mraw >> (8 * e))), at[jf][e], s);
      s += __shfl_xor(s, 16, 64);
      s += __shfl_xor(s, 32, 64);
      if (lk == 0) atomicAdd(&dsig[lq], s);
    }
    __syncthreads();
  }

  // ---------- c3 phase ----------
  if (tid < 256) {
    float ds = dsig[tid] + s2L[tid];
    float rs = rsqrtf(ds);
    float xb = tanhf(SQ2PI_F * h3bar[b * 256 + tid] * rs);
    x3bar[b * 256 + tid] = xb;
    float d = 1.f - xb * xb;
    c3L[tid] = d * rs;
    d3L[tid] = d;
  }
  __syncthreads();

  // ---------- SIG loop: sigma3 (fp8 MFMA) + fused epilogue, barrier-free ----------
  long am2[8];
#pragma unroll
  for (int ks = 0; ks < 8; ++ks)
    am2[ks] = *(const long*)(m2f8 + (size_t)(R + lr) * 256 + ks * 32 + lk * 8);

#pragma unroll
  for (int lp = 0; lp < 4; ++lp) {
    f32x4 sc[4];
#pragma unroll
    for (int j = 0; j < 4; ++j) sc[j] = {0.f, 0.f, 0.f, 0.f};
#pragma unroll
    for (int ks = 0; ks < 8; ++ks) {
#pragma unroll
      for (int j = 0; j < 4; ++j) {
        int p = lp * 64 + j * 16 + lr;
        long bq = *(const long*)(XC + (size_t)p * 264 + (ks * 4 + lk) * 8);
        sc[j] = __builtin_amdgcn_mfma_f32_16x16x32_fp8_fp8(am2[ks], bq, sc[j], 0, 0, 0);
      }
    }
    int i0 = R + lk * 4;
#pragma unroll
    for (int lf = 0; lf < 4; ++lf) {
      int gl = lp * 64 + lf * 16 + lr;
      float cg = c3L[gl];
      f32x4 st;
#pragma unroll
      for (int e = 0; e < 4; ++e) {
        int i = i0 + e;
        float g = sc[lf][e];
        if (i == gl) g += s2L[i];
        float v = SQ2PI_F * c3L[i] * cg * g;
        if (i == gl) v += d3L[i];
        st[e] = v;
      }
      *(f32x4*)(xcov3 + ((size_t)b << 16) + (size_t)gl * 256 + i0) = st;
    }
  }
#undef PRD8
}

// final layer + log_softmax + loss + frac_correct. grid 4 x block 64
__global__ void k_final4(const float* __restrict__ x3bar, const float* __restrict__ mlast,
                         const float* __restrict__ thlast, const int* __restrict__ target,
                         float* __restrict__ hlast_out, float* __restrict__ logp_out,
                         float* __restrict__ loss_out, float* __restrict__ frac_out) {
  __shared__ float Wl[2560];
  int t = threadIdx.x;
  int r = blockIdx.x * 64 + t;
  for (int p = t; p < 2560; p += 64) Wl[p] = mlast[p];
  __syncthreads();
  float acc[10];
#pragma unroll
  for (int c = 0; c < 10; ++c) acc[c] = thlast[c];
  for (int j = 0; j < 256; ++j) {
    float xv = x3bar[r * 256 + j];
#pragma unroll
    for (int c = 0; c < 10; ++c) acc[c] = fmaf(xv, Wl[j * 10 + c], acc[c]);
  }
#pragma unroll
  for (int c = 0; c < 10; ++c) hlast_out[r * 10 + c] = acc[c];
  float mx = acc[0];
  int am = 0;
#pragma unroll
  for (int c = 1; c < 10; ++c)
    if (acc[c] > mx) { mx = acc[c]; am = c; }
  float se = 0.f;
#pragma unroll
  for (int c = 0; c < 10; ++c) se += expf(acc[c] - mx);
  float lse = logf(se);
#pragma unroll
  for (int c = 0; c < 10; ++c) logp_out[r * 10 + c] = acc[c] - mx - lse;
  int tg = target[r];
  float lossc = -(acc[tg] - mx - lse) * (1.f / 256.f);
  float corr = (am == tg) ? (1.f / 256.f) : 0.f;
#pragma unroll
  for (int off = 32; off > 0; off >>= 1) {
    lossc += __shfl_down(lossc, off);
    corr += __shfl_down(corr, off);
  }
  if (t == 0) {
    atomicAdd(loss_out, lossc);
    atomicAdd(frac_out, corr);
  }
}

// ------------------------------------------------------------------

extern "C" void kernel_launch(void* const* d_in, const int* in_sizes, int n_in,
                              void* d_out, int out_size, void* d_ws, size_t ws_size,
                              hipStream_t stream) {
  const float* x = (const float*)d_in[0];
  const int* target = (const int*)d_in[1];
  const float* w0 = (const float*)d_in[2];
  const float* w1 = (const float*)d_in[3];
  const float* w2 = (const float*)d_in[4];
  const float* wlast = (const float*)d_in[5];
  const float* th0 = (const float*)d_in[6];
  const float* th1 = (const float*)d_in[7];
  const float* th2 = (const float*)d_in[8];
  const float* thlast = (const float*)d_in[9];

  float* W = (float*)d_ws;
  size_t o = 0;
  auto alloc = [&](size_t n) { float* p = W + o; o += n; return p; };
  float* m0 = alloc(200704);
  float* m1 = alloc(65536);
  float* m2 = alloc(65536);
  float* mlast = alloc(2560);
  float* s1 = alloc(256);
  float* s2 = alloc(256);
  float* x1bar = alloc(65536);
  float* d1 = alloc(65536);
  float* c2 = alloc(65536);
  float* d2p = alloc(65536);
  float* h3bar = alloc(65536);
  float* x3bar = alloc(65536);
  unsigned char* m1f8t = (unsigned char*)alloc(16384);  // 65536 fp8
  unsigned char* m2f8 = (unsigned char*)alloc(16384);   // 65536 fp8

  float* hlast = (float*)d_out;
  float* logp = hlast + 2560;
  float* xcov3_out = logp + 2560;
  float* loss = xcov3_out + 16777216;
  float* frac = loss + 1;

  // 1) prep (means + fp8 transposes + zero loss/frac)
  k_prep<<<1306, 256, 0, stream>>>(w0, w1, w2, wlast, m0, m1, m1f8t, m2, m2f8,
                                   mlast, loss);
  // 2) layer 1 (split-k, diagsig1 folded)
  k_layer1<<<256, 512, 0, stream>>>(x, m0, th0, x1bar, d1);
  // 3) layer 2 (+h3, s1/s2 folded)
  k_layer2<<<256, 512, 0, stream>>>(d1, x1bar, m1, m2, th1, th2, c2, d2p,
                                    h3bar, s1, s2);
  // 4) fused sigma-chain (full fp8 operands; spill-free state budget)
  k_fused<<<256, 1024, 0, stream>>>(m1f8t, m2f8, d1, c2, d2p, s1, s2,
                                    h3bar, x3bar, xcov3_out);
  // 5) final layer + softmax + loss + acc
  k_final4<<<4, 64, 0, stream>>>(x3bar, mlast, thlast, target, hlast, logp, loss, frac);
}

// Round 15
// 129.444 us; speedup vs baseline: 1.0722x; 1.0429x over previous
//
#include <hip/hip_runtime.h>
#include <hip/hip_fp8.h>
#include <math.h>

#define SQ2PI_F 0.79788456f

typedef __attribute__((ext_vector_type(4))) float f32x4;
typedef __attribute__((address_space(1))) unsigned int gas_u32;
typedef __attribute__((address_space(3))) unsigned int las_u32;

__device__ inline unsigned char f2fp8(float v) { return __hip_fp8_e4m3(v).__x; }
__device__ inline float fp8tof(unsigned char b) {
  __hip_fp8_e4m3 h;
  h.__x = (__hip_fp8_storage_t)b;
  return (float)h;
}
__device__ inline unsigned int pk_fp8x4(f32x4 v) {
  return (unsigned int)f2fp8(v[0]) | ((unsigned int)f2fp8(v[1]) << 8) |
         ((unsigned int)f2fp8(v[2]) << 16) | ((unsigned int)f2fp8(v[3]) << 24);
}

// ------------------------------------------------------------------
// prep: means + fp8 transposes; zero loss/frac
// ------------------------------------------------------------------
__global__ void k_prep(const float* __restrict__ w0, const float* __restrict__ w1,
                       const float* __restrict__ w2, const float* __restrict__ wlast,
                       float* __restrict__ m0, float* __restrict__ m1,
                       unsigned char* __restrict__ m1f8t, float* __restrict__ m2,
                       unsigned char* __restrict__ m2f8, float* __restrict__ mlast,
                       float* __restrict__ lf) {
  int b = blockIdx.x, t = threadIdx.x;
  if (b < 784) {
    int i = b * 256 + t;
    m0[i] = tanhf(0.5f * w0[i]);
  } else if (b < 1040) {
    int j = b - 784;
    float v = tanhf(0.5f * w1[j * 256 + t]);
    m1[j * 256 + t] = v;
    m1f8t[t * 256 + j] = f2fp8(v);    // m1f8t[r][k] = m1[k][r]
  } else if (b < 1296) {
    int j = b - 1040;
    float v = tanhf(0.5f * w2[j * 256 + t]);
    m2[j * 256 + t] = v;
    m2f8[t * 256 + j] = f2fp8(v);     // m2f8[i][j] = m2[j][i]
  } else {
    int i = (b - 1296) * 256 + t;
    if (i < 2560) mlast[i] = tanhf(0.5f * wlast[i]);
    if (b == 1296 && t < 2) lf[t] = 0.f;
  }
}

// ------------------------------------------------------------------
// fused layers 1+2(+h3): block=row r, 512 thr split-k. x1bar stays in LDS.
// emits d1 (global, for k_fused), c2, d2p, h3bar, s1/s2 (block 0).
// ------------------------------------------------------------------
__global__ void k_layers(const float* __restrict__ x, const float* __restrict__ m0,
                         const float* __restrict__ m1, const float* __restrict__ m2,
                         const float* __restrict__ th0, const float* __restrict__ th1,
                         const float* __restrict__ th2,
                         float* __restrict__ d1g, float* __restrict__ c2,
                         float* __restrict__ d2p, float* __restrict__ h3bar,
                         float* __restrict__ s1g, float* __restrict__ s2g) {
  __shared__ float xr[784];
  __shared__ float pa[256], pb[256], pc[256];
  __shared__ float sx1[256], sd1[256], sx2[256];
  int r = blockIdx.x, t = threadIdx.x;
  int i = t & 255, h = t >> 8;
  for (int p = t; p < 784; p += 512) xr[p] = x[r * 784 + p];
  __syncthreads();
  // layer 1 (diagsig1 folded)
  {
    float acch = 0.f, accd = 0.f;
    int k0 = h * 392, k1 = k0 + 392;
#pragma unroll 8
    for (int k = k0; k < k1; ++k) {
      float mm = m0[k * 256 + i];
      acch = fmaf(xr[k], mm, acch);
      accd = fmaf(-mm, mm, accd + 1.f);
    }
    if (h) { pa[i] = acch; pb[i] = accd; }
    __syncthreads();
    if (!h) {
      acch += pa[i];
      accd += pb[i];
      float rs = rsqrtf(accd);
      float xb = tanhf(SQ2PI_F * (acch + th0[i]) * rs);
      float d = 1.f - xb * xb;
      sx1[i] = xb;
      sd1[i] = d;
      d1g[r * 256 + i] = d;
    }
    __syncthreads();
  }
  // layer 2 (s1 folded)
  {
    float accd = 0.f, acch = 0.f, accs = 0.f;
    int j0 = h * 128, j1 = j0 + 128;
    for (int j = j0; j < j1; ++j) {
      float mm = m1[j * 256 + i];
      accd = fmaf(sd1[j] * mm, mm, accd);
      acch = fmaf(sx1[j], mm, acch);
      accs = fmaf(-mm, mm, accs + 1.f);
    }
    if (h) { pa[i] = accd; pb[i] = acch; pc[i] = accs; }
    __syncthreads();
    if (!h) {
      accd += pa[i];
      acch += pb[i];
      accs += pc[i];
      float rs = rsqrtf(accd + accs);
      float xb = tanhf(SQ2PI_F * (acch + th1[i]) * rs);
      float d = 1.f - xb * xb;
      c2[r * 256 + i] = d * rs;
      d2p[r * 256 + i] = d;
      sx2[i] = xb;
      if (r == 0) s1g[i] = accs;
    }
    __syncthreads();
  }
  // h3 (s2 folded)
  {
    float acc3 = 0.f, acc2 = 0.f;
    int j0 = h * 128, j1 = j0 + 128;
    for (int j = j0; j < j1; ++j) {
      float mm = m2[j * 256 + i];
      acc3 = fmaf(sx2[j], mm, acc3);
      acc2 = fmaf(-mm, mm, acc2 + 1.f);
    }
    if (h) { pa[i] = acc3; pb[i] = acc2; }
    __syncthreads();
    if (!h) {
      h3bar[r * 256 + i] = acc3 + pa[i] + th2[i];
      if (r == 0) s2g[i] = acc2 + pb[i];
    }
  }
}

// ------------------------------------------------------------------
// k_fused (fp8, m2-resident): 1024 thr / 16 waves per batch, wave owns
// 16 output rows. m2f8 (64KB) staged ONCE into m2L -> T3 and SIG run
// BARRIER-FREE (B-operands from resident LDS; XC visibility needs only
// the single pre-c3 barrier). Phase 1 keeps dbuf-staged m1 panels
// (8 x 32-col segments). XB exchange aliases XC[0:16KB] (guard barrier
// after phase 1 before T3 overwrites).
// Swizzle (all 256B-row buffers, 8B granules): granule g of row p lives
// at slot g ^ ((p&7)<<1); gload source uses the equivalent 16B-chunk
// form c ^ (p&7). Same XOR on write and read (rule 21).
// MFMA fp8 16x16x32 frags: A[row=lr][k@lk*8], B[col=lr][k@lk*8],
// C rows lk*4+e, cols lr (HW-validated rounds 12-14).
// ------------------------------------------------------------------
__global__ __launch_bounds__(1024, 4) void k_fused(
    const unsigned char* __restrict__ m1f8t, const unsigned char* __restrict__ m2f8,
    const float* __restrict__ d1, const float* __restrict__ c2,
    const float* __restrict__ d2p, const float* __restrict__ s1,
    const float* __restrict__ s2, const float* __restrict__ h3bar,
    float* __restrict__ x3bar, float* __restrict__ xcov3) {
  __shared__ __align__(16) unsigned char m2L[65536];  // resident m2^T fp8
  __shared__ __align__(16) unsigned char XC[65536];   // t3^T fp8 (XB aliases head)
  __shared__ __align__(16) unsigned char SB[2][8192]; // staged m1 panels (32 rows)
  __shared__ float c2L[256], d2pL[256], s1L[256], s2L[256];
  __shared__ float dsig[256], c3L[256], d3L[256];

  const int b = blockIdx.x;
  const int tid = threadIdx.x;
  const int l = tid & 63, w = tid >> 6;  // 16 waves
  const int lr = l & 15, lk = l >> 4;
  const int R = w * 16;

// logical 8B granule kc (0..31) of row p in a swizzled 256B-row buffer
#define PRD8(S, p, kc) \
  (*(const long*)((const unsigned char*)(S) + ((p) << 8) + ((((kc) ^ (((p) & 7) << 1))) << 3)))
// byte offset for a u32 store of logical bytes [j0, j0+4) (j0 % 4 == 0)
#define SWZ32(p, j0) (((p) << 8) + ((((j0) >> 3) ^ (((p) & 7) << 1)) << 3) + ((j0) & 7))

  // ---- stage m2L (all 256 rows, 4 rounds x 1 load/lane) ----
#pragma unroll
  for (int q = 0; q < 4; ++q) {
    int rl = q * 64 + w * 4 + (l >> 4);
    int c = l & 15;
    const unsigned char* src = m2f8 + rl * 256 + ((c ^ (rl & 7)) << 4);
    unsigned char* dst = m2L + (q * 64 + w * 4) * 256;
    __builtin_amdgcn_global_load_lds((const gas_u32*)src, (las_u32*)dst, 16, 0, 0);
  }
  // ---- stage SB[0] = m1 panel 0 (32 rows; waves 0..7) ----
  if (w < 8) {
    int rl = w * 4 + (l >> 4);
    int c = l & 15;
    const unsigned char* src = m1f8t + rl * 256 + ((c ^ (rl & 7)) << 4);
    __builtin_amdgcn_global_load_lds((const gas_u32*)src,
                                     (las_u32*)(SB[0] + (w * 4) * 256), 16, 0, 0);
  }

  if (tid < 256) {
    c2L[tid] = c2[b * 256 + tid];
    d2pL[tid] = d2p[b * 256 + tid];
    s1L[tid] = s1[tid];
    s2L[tid] = s2[tid];
    dsig[tid] = 0.f;
  }

  const float* d1b = d1 + b * 256;

  // hoisted, d1-weighted phase-1 A-frags (fp8, wave's 16 rows)
  long af_w[8];
#pragma unroll
  for (int ks = 0; ks < 8; ++ks) {
    unsigned long long mr =
        *(const unsigned long long*)(m1f8t + (size_t)(R + lr) * 256 + ks * 32 + lk * 8);
    const float* dp = d1b + ks * 32 + lk * 8;
    unsigned long long out = 0;
#pragma unroll
    for (int e = 0; e < 8; ++e) {
      float v = fp8tof((unsigned char)(mr >> (8 * e))) * dp[e];
      out |= ((unsigned long long)f2fp8(v)) << (8 * e);
    }
    af_w[ks] = (long)out;
  }
  __syncthreads();  // m2L + SB[0] staged, vectors visible

  long afX[8];  // wave's 16 xcov2 rows (fp8 A-frags)

  // ---------- phase 1: xcov2, 8 segments of 32 cols ----------
#pragma unroll
  for (int cp = 0; cp < 8; ++cp) {
    if (cp < 7 && w < 8) {
      int rl = w * 4 + (l >> 4);
      int c = l & 15;
      const unsigned char* src =
          m1f8t + (size_t)(cp + 1) * 8192 + rl * 256 + ((c ^ (rl & 7)) << 4);
      __builtin_amdgcn_global_load_lds(
          (const gas_u32*)src, (las_u32*)(SB[(cp + 1) & 1] + (w * 4) * 256), 16, 0, 0);
    }
    const unsigned char* sbc = SB[cp & 1];
    f32x4 acc[2];
    acc[0] = {0.f, 0.f, 0.f, 0.f};
    acc[1] = {0.f, 0.f, 0.f, 0.f};
#pragma unroll
    for (int ks = 0; ks < 8; ++ks) {
      long bq0 = PRD8(sbc, lr, ks * 4 + lk);
      long bq1 = PRD8(sbc, 16 + lr, ks * 4 + lk);
      acc[0] = __builtin_amdgcn_mfma_f32_16x16x32_fp8_fp8(af_w[ks], bq0, acc[0], 0, 0, 0);
      acc[1] = __builtin_amdgcn_mfma_f32_16x16x32_fp8_fp8(af_w[ks], bq1, acc[1], 0, 0, 0);
    }
    unsigned char* XP = XC + (cp & 1) * 8192;  // XB dbuf aliases XC head
    int r0 = R + lk * 4;
#pragma unroll
    for (int j = 0; j < 2; ++j) {
      int p = j * 16 + lr;
      int cc = cp * 32 + p;
      float c2c = c2L[cc];
      f32x4 st;
#pragma unroll
      for (int e = 0; e < 4; ++e) {
        int r = r0 + e;
        float g = acc[j][e];
        if (r == cc) g += s1L[r];
        float v = SQ2PI_F * c2L[r] * c2c * g;
        if (r == cc) v += d2pL[r];
        st[e] = v;
      }
      // transposed-symmetric fp8 store: XB[p][logical bytes r0..r0+3]
      *(unsigned int*)(XP + SWZ32(p, r0)) = pk_fp8x4(st);
    }
    __syncthreads();
    if (cp == (w >> 1)) {
      int p2 = (w & 1) * 16 + lr;
#pragma unroll
      for (int ks = 0; ks < 8; ++ks) afX[ks] = PRD8(XP, p2, ks * 4 + lk);
    }
  }
  __syncthreads();  // all afX pulls done before T3 overwrites XC head

  // ---------- T3: barrier-free; t3^T -> XC fp8 + fused diag ----------
#pragma unroll
  for (int lf = 0; lf < 16; ++lf) {
    f32x4 at = {0.f, 0.f, 0.f, 0.f};
#pragma unroll
    for (int ks = 0; ks < 8; ++ks) {
      long bq = PRD8(m2L, lf * 16 + lr, ks * 4 + lk);
      at = __builtin_amdgcn_mfma_f32_16x16x32_fp8_fp8(afX[ks], bq, at, 0, 0, 0);
    }
    int j0 = R + lk * 4;
    int lq = lf * 16 + lr;  // global t3 column
    *(unsigned int*)(XC + SWZ32(lq, j0)) = pk_fp8x4(at);
    // diag partial: m2t[lq][j0..j0+3] from resident m2L; pre-rounding f32 t3
    unsigned int mraw = *(const unsigned int*)(m2L + SWZ32(lq, j0));
    float s = 0.f;
#pragma unroll
    for (int e = 0; e < 4; ++e)
      s = fmaf(fp8tof((unsigned char)(mraw >> (8 * e))), at[e], s);
    s += __shfl_xor(s, 16, 64);
    s += __shfl_xor(s, 32, 64);
    if (lk == 0) atomicAdd(&dsig[lq], s);
  }
  __syncthreads();

  // ---------- c3 phase ----------
  if (tid < 256) {
    float ds = dsig[tid] + s2L[tid];
    float rs = rsqrtf(ds);
    float xb = tanhf(SQ2PI_F * h3bar[b * 256 + tid] * rs);
    x3bar[b * 256 + tid] = xb;
    float d = 1.f - xb * xb;
    c3L[tid] = d * rs;
    d3L[tid] = d;
  }
  __syncthreads();

  // ---------- SIG: barrier-free; sigma3 + fused epilogue -> d_out ----------
  long am2[8];
#pragma unroll
  for (int ks = 0; ks < 8; ++ks) am2[ks] = PRD8(m2L, R + lr, ks * 4 + lk);

#pragma unroll
  for (int lf = 0; lf < 16; ++lf) {
    f32x4 sc = {0.f, 0.f, 0.f, 0.f};
    int p = lf * 16 + lr;
#pragma unroll
    for (int ks = 0; ks < 8; ++ks) {
      long bq = PRD8(XC, p, ks * 4 + lk);
      sc = __builtin_amdgcn_mfma_f32_16x16x32_fp8_fp8(am2[ks], bq, sc, 0, 0, 0);
    }
    int i0 = R + lk * 4;
    int gl = p;
    float cg = c3L[gl];
    f32x4 st;
#pragma unroll
    for (int e = 0; e < 4; ++e) {
      int i = i0 + e;
      float g = sc[e];
      if (i == gl) g += s2L[i];
      float v = SQ2PI_F * c3L[i] * cg * g;
      if (i == gl) v += d3L[i];
      st[e] = v;
    }
    *(f32x4*)(xcov3 + ((size_t)b << 16) + (size_t)gl * 256 + i0) = st;
  }
#undef PRD8
#undef SWZ32
}

// final layer + log_softmax + loss + frac_correct. grid 4 x block 64
__global__ void k_final4(const float* __restrict__ x3bar, const float* __restrict__ mlast,
                         const float* __restrict__ thlast, const int* __restrict__ target,
                         float* __restrict__ hlast_out, float* __restrict__ logp_out,
                         float* __restrict__ loss_out, float* __restrict__ frac_out) {
  __shared__ float Wl[2560];
  int t = threadIdx.x;
  int r = blockIdx.x * 64 + t;
  for (int p = t; p < 2560; p += 64) Wl[p] = mlast[p];
  __syncthreads();
  float acc[10];
#pragma unroll
  for (int c = 0; c < 10; ++c) acc[c] = thlast[c];
  for (int j = 0; j < 256; ++j) {
    float xv = x3bar[r * 256 + j];
#pragma unroll
    for (int c = 0; c < 10; ++c) acc[c] = fmaf(xv, Wl[j * 10 + c], acc[c]);
  }
#pragma unroll
  for (int c = 0; c < 10; ++c) hlast_out[r * 10 + c] = acc[c];
  float mx = acc[0];
  int am = 0;
#pragma unroll
  for (int c = 1; c < 10; ++c)
    if (acc[c] > mx) { mx = acc[c]; am = c; }
  float se = 0.f;
#pragma unroll
  for (int c = 0; c < 10; ++c) se += expf(acc[c] - mx);
  float lse = logf(se);
#pragma unroll
  for (int c = 0; c < 10; ++c) logp_out[r * 10 + c] = acc[c] - mx - lse;
  int tg = target[r];
  float lossc = -(acc[tg] - mx - lse) * (1.f / 256.f);
  float corr = (am == tg) ? (1.f / 256.f) : 0.f;
#pragma unroll
  for (int off = 32; off > 0; off >>= 1) {
    lossc += __shfl_down(lossc, off);
    corr += __shfl_down(corr, off);
  }
  if (t == 0) {
    atomicAdd(loss_out, lossc);
    atomicAdd(frac_out, corr);
  }
}

// ------------------------------------------------------------------

extern "C" void kernel_launch(void* const* d_in, const int* in_sizes, int n_in,
                              void* d_out, int out_size, void* d_ws, size_t ws_size,
                              hipStream_t stream) {
  const float* x = (const float*)d_in[0];
  const int* target = (const int*)d_in[1];
  const float* w0 = (const float*)d_in[2];
  const float* w1 = (const float*)d_in[3];
  const float* w2 = (const float*)d_in[4];
  const float* wlast = (const float*)d_in[5];
  const float* th0 = (const float*)d_in[6];
  const float* th1 = (const float*)d_in[7];
  const float* th2 = (const float*)d_in[8];
  const float* thlast = (const float*)d_in[9];

  float* W = (float*)d_ws;
  size_t o = 0;
  auto alloc = [&](size_t n) { float* p = W + o; o += n; return p; };
  float* m0 = alloc(200704);
  float* m1 = alloc(65536);
  float* m2 = alloc(65536);
  float* mlast = alloc(2560);
  float* s1 = alloc(256);
  float* s2 = alloc(256);
  float* d1 = alloc(65536);
  float* c2 = alloc(65536);
  float* d2p = alloc(65536);
  float* h3bar = alloc(65536);
  float* x3bar = alloc(65536);
  unsigned char* m1f8t = (unsigned char*)alloc(16384);  // 65536 fp8
  unsigned char* m2f8 = (unsigned char*)alloc(16384);   // 65536 fp8

  float* hlast = (float*)d_out;
  float* logp = hlast + 2560;
  float* xcov3_out = logp + 2560;
  float* loss = xcov3_out + 16777216;
  float* frac = loss + 1;

  // 1) prep (means + fp8 transposes + zero loss/frac)
  k_prep<<<1306, 256, 0, stream>>>(w0, w1, w2, wlast, m0, m1, m1f8t, m2, m2f8,
                                   mlast, loss);
  // 2) layers 1+2 (+h3) fused; x1bar stays in LDS
  k_layers<<<256, 512, 0, stream>>>(x, m0, m1, m2, th0, th1, th2, d1, c2, d2p,
                                    h3bar, s1, s2);
  // 3) fused sigma-chain (m2 LDS-resident; T3/SIG barrier-free)
  k_fused<<<256, 1024, 0, stream>>>(m1f8t, m2f8, d1, c2, d2p, s1, s2,
                                    h3bar, x3bar, xcov3_out);
  // 4) final layer + softmax + loss + acc
  k_final4<<<4, 64, 0, stream>>>(x3bar, mlast, thlast, target, hlast, logp, loss, frac);
}

// Round 16
// 122.476 us; speedup vs baseline: 1.1332x; 1.0569x over previous
//
#include <hip/hip_runtime.h>
#include <hip/hip_fp8.h>
#include <math.h>

#define SQ2PI_F 0.79788456f

typedef __attribute__((ext_vector_type(4))) float f32x4;
typedef __attribute__((address_space(1))) unsigned int gas_u32;
typedef __attribute__((address_space(3))) unsigned int las_u32;

#if defined(__has_builtin)
#if __has_builtin(__builtin_amdgcn_cvt_pk_fp8_f32) && __has_builtin(__builtin_amdgcn_cvt_f32_fp8)
#define HW_FP8 1
#endif
#endif

__device__ inline unsigned char f2fp8(float v) { return __hip_fp8_e4m3(v).__x; }

__device__ inline unsigned int pk_fp8x4(f32x4 v) {
#ifdef HW_FP8
  int r = 0;
  r = __builtin_amdgcn_cvt_pk_fp8_f32(v[0], v[1], r, false);
  r = __builtin_amdgcn_cvt_pk_fp8_f32(v[2], v[3], r, true);
  return (unsigned int)r;
#else
  return (unsigned int)f2fp8(v[0]) | ((unsigned int)f2fp8(v[1]) << 8) |
         ((unsigned int)f2fp8(v[2]) << 16) | ((unsigned int)f2fp8(v[3]) << 24);
#endif
}

__device__ inline f32x4 upk_fp8x4(unsigned int r) {
  f32x4 o;
#ifdef HW_FP8
  o[0] = __builtin_amdgcn_cvt_f32_fp8((int)r, 0);
  o[1] = __builtin_amdgcn_cvt_f32_fp8((int)r, 1);
  o[2] = __builtin_amdgcn_cvt_f32_fp8((int)r, 2);
  o[3] = __builtin_amdgcn_cvt_f32_fp8((int)r, 3);
#else
  __hip_fp8_e4m3 h;
#pragma unroll
  for (int e = 0; e < 4; ++e) {
    h.__x = (__hip_fp8_storage_t)((r >> (8 * e)) & 0xff);
    o[e] = (float)h;
  }
#endif
  return o;
}

// ------------------------------------------------------------------
// prep: means + fp8 transposes; zero loss/frac
// ------------------------------------------------------------------
__global__ void k_prep(const float* __restrict__ w0, const float* __restrict__ w1,
                       const float* __restrict__ w2, const float* __restrict__ wlast,
                       float* __restrict__ m0, float* __restrict__ m1,
                       unsigned char* __restrict__ m1f8t, float* __restrict__ m2,
                       unsigned char* __restrict__ m2f8, float* __restrict__ mlast,
                       float* __restrict__ lf) {
  int b = blockIdx.x, t = threadIdx.x;
  if (b < 784) {
    int i = b * 256 + t;
    m0[i] = tanhf(0.5f * w0[i]);
  } else if (b < 1040) {
    int j = b - 784;
    float v = tanhf(0.5f * w1[j * 256 + t]);
    m1[j * 256 + t] = v;
    m1f8t[t * 256 + j] = f2fp8(v);    // m1f8t[r][k] = m1[k][r]
  } else if (b < 1296) {
    int j = b - 1040;
    float v = tanhf(0.5f * w2[j * 256 + t]);
    m2[j * 256 + t] = v;
    m2f8[t * 256 + j] = f2fp8(v);     // m2f8[i][j] = m2[j][i]
  } else {
    int i = (b - 1296) * 256 + t;
    if (i < 2560) mlast[i] = tanhf(0.5f * wlast[i]);
    if (b == 1296 && t < 2) lf[t] = 0.f;
  }
}

// ------------------------------------------------------------------
// fused layers 1+2(+h3): block=row r, 512 thr split-k. x1bar stays in LDS.
// ------------------------------------------------------------------
__global__ void k_layers(const float* __restrict__ x, const float* __restrict__ m0,
                         const float* __restrict__ m1, const float* __restrict__ m2,
                         const float* __restrict__ th0, const float* __restrict__ th1,
                         const float* __restrict__ th2,
                         float* __restrict__ d1g, float* __restrict__ c2,
                         float* __restrict__ d2p, float* __restrict__ h3bar,
                         float* __restrict__ s1g, float* __restrict__ s2g) {
  __shared__ float xr[784];
  __shared__ float pa[256], pb[256], pc[256];
  __shared__ float sx1[256], sd1[256], sx2[256];
  int r = blockIdx.x, t = threadIdx.x;
  int i = t & 255, h = t >> 8;
  for (int p = t; p < 784; p += 512) xr[p] = x[r * 784 + p];
  __syncthreads();
  {
    float acch = 0.f, accd = 0.f;
    int k0 = h * 392, k1 = k0 + 392;
#pragma unroll 8
    for (int k = k0; k < k1; ++k) {
      float mm = m0[k * 256 + i];
      acch = fmaf(xr[k], mm, acch);
      accd = fmaf(-mm, mm, accd + 1.f);
    }
    if (h) { pa[i] = acch; pb[i] = accd; }
    __syncthreads();
    if (!h) {
      acch += pa[i];
      accd += pb[i];
      float rs = rsqrtf(accd);
      float xb = tanhf(SQ2PI_F * (acch + th0[i]) * rs);
      float d = 1.f - xb * xb;
      sx1[i] = xb;
      sd1[i] = d;
      d1g[r * 256 + i] = d;
    }
    __syncthreads();
  }
  {
    float accd = 0.f, acch = 0.f, accs = 0.f;
    int j0 = h * 128, j1 = j0 + 128;
    for (int j = j0; j < j1; ++j) {
      float mm = m1[j * 256 + i];
      accd = fmaf(sd1[j] * mm, mm, accd);
      acch = fmaf(sx1[j], mm, acch);
      accs = fmaf(-mm, mm, accs + 1.f);
    }
    if (h) { pa[i] = accd; pb[i] = acch; pc[i] = accs; }
    __syncthreads();
    if (!h) {
      accd += pa[i];
      acch += pb[i];
      accs += pc[i];
      float rs = rsqrtf(accd + accs);
      float xb = tanhf(SQ2PI_F * (acch + th1[i]) * rs);
      float d = 1.f - xb * xb;
      c2[r * 256 + i] = d * rs;
      d2p[r * 256 + i] = d;
      sx2[i] = xb;
      if (r == 0) s1g[i] = accs;
    }
    __syncthreads();
  }
  {
    float acc3 = 0.f, acc2 = 0.f;
    int j0 = h * 128, j1 = j0 + 128;
    for (int j = j0; j < j1; ++j) {
      float mm = m2[j * 256 + i];
      acc3 = fmaf(sx2[j], mm, acc3);
      acc2 = fmaf(-mm, mm, acc2 + 1.f);
    }
    if (h) { pa[i] = acc3; pb[i] = acc2; }
    __syncthreads();
    if (!h) {
      h3bar[r * 256 + i] = acc3 + pa[i] + th2[i];
      if (r == 0) s2g[i] = acc2 + pb[i];
    }
  }
}

// ------------------------------------------------------------------
// k_fused (fp8, m2-resident, 2x-MFMA-per-read): 1024 thr / 16 waves per
// batch. Wave = (wr 0..7, wc 0..1): owns 32 output rows (2 A-frags) x
// half the cols -> every B-frag ds_read feeds 2 MFMAs into 2 INDEPENDENT
// accumulators (breaks the 8-deep MFMA latency chain, halves LDS reads).
//   phase 1 (8 x 32-col segs, dbuf-staged m1): cols wc*16+lr of seg.
//   afX pull at seg cp==wr: both 16-row groups (16 longs).
//   T3 (barrier-free): cols wc*128 + lf*16; t3^T -> XC fp8 + fused diag.
//   SIG (barrier-free): sigma3 + epilogue -> d_out.
// fp8 pack/unpack use HW builtins (cvt_pk_fp8_f32 / cvt_f32_fp8).
// Swizzle: granule g of row p at slot g ^ ((p&7)<<1); gload source chunk
// c ^ (p&7) (same XOR both sides, rule 21). MFMA fp8 16x16x32 frags:
// A[row=lr][k@lk*8], B[col=lr][k@lk*8], C rows lk*4+e cols lr (HW-valid
// rounds 12-15).
// ------------------------------------------------------------------
__global__ __launch_bounds__(1024, 4) void k_fused(
    const unsigned char* __restrict__ m1f8t, const unsigned char* __restrict__ m2f8,
    const float* __restrict__ d1, const float* __restrict__ c2,
    const float* __restrict__ d2p, const float* __restrict__ s1,
    const float* __restrict__ s2, const float* __restrict__ h3bar,
    float* __restrict__ x3bar, float* __restrict__ xcov3) {
  __shared__ __align__(16) unsigned char m2L[65536];  // resident m2^T fp8
  __shared__ __align__(16) unsigned char XC[65536];   // t3^T fp8 (XB aliases head)
  __shared__ __align__(16) unsigned char SB[2][8192]; // staged m1 panels (32 rows)
  __shared__ float c2L[256], d2pL[256], s1L[256], s2L[256];
  __shared__ float dsig[256], c3L[256], d3L[256];

  const int b = blockIdx.x;
  const int tid = threadIdx.x;
  const int l = tid & 63, w = tid >> 6;  // 16 waves
  const int lr = l & 15, lk = l >> 4;
  const int wr = w >> 1, wc = w & 1;
  const int R32 = wr * 32;

// logical 8B granule kc (0..31) of row p in a swizzled 256B-row buffer
#define PRD8(S, p, kc) \
  (*(const long*)((const unsigned char*)(S) + ((p) << 8) + ((((kc) ^ (((p) & 7) << 1))) << 3)))
// byte offset for a u32 access of logical bytes [j0, j0+4) (j0 % 4 == 0)
#define SWZ32(p, j0) (((p) << 8) + ((((j0) >> 3) ^ (((p) & 7) << 1)) << 3) + ((j0) & 7))

  // ---- stage m2L (256 rows, 4 rounds x 1 load/lane) ----
#pragma unroll
  for (int q = 0; q < 4; ++q) {
    int rl = q * 64 + w * 4 + (l >> 4);
    int c = l & 15;
    const unsigned char* src = m2f8 + rl * 256 + ((c ^ (rl & 7)) << 4);
    unsigned char* dst = m2L + (q * 64 + w * 4) * 256;
    __builtin_amdgcn_global_load_lds((const gas_u32*)src, (las_u32*)dst, 16, 0, 0);
  }
  // ---- stage SB[0] = m1 panel 0 (32 rows; waves 0..7) ----
  if (w < 8) {
    int rl = w * 4 + (l >> 4);
    int c = l & 15;
    const unsigned char* src = m1f8t + rl * 256 + ((c ^ (rl & 7)) << 4);
    __builtin_amdgcn_global_load_lds((const gas_u32*)src,
                                     (las_u32*)(SB[0] + (w * 4) * 256), 16, 0, 0);
  }

  if (tid < 256) {
    c2L[tid] = c2[b * 256 + tid];
    d2pL[tid] = d2p[b * 256 + tid];
    s1L[tid] = s1[tid];
    s2L[tid] = s2[tid];
    dsig[tid] = 0.f;
  }

  const float* d1b = d1 + b * 256;

  // hoisted, d1-weighted phase-1 A-frags (fp8, wave's 32 rows: 2 groups)
  long af_w[16];
#pragma unroll
  for (int f = 0; f < 2; ++f) {
#pragma unroll
    for (int ks = 0; ks < 8; ++ks) {
      unsigned long long mr = *(const unsigned long long*)(
          m1f8t + (size_t)(R32 + f * 16 + lr) * 256 + ks * 32 + lk * 8);
      f32x4 w0 = upk_fp8x4((unsigned int)mr);
      f32x4 w1 = upk_fp8x4((unsigned int)(mr >> 32));
      f32x4 dv0 = *(const f32x4*)(d1b + ks * 32 + lk * 8);
      f32x4 dv1 = *(const f32x4*)(d1b + ks * 32 + lk * 8 + 4);
      f32x4 v0, v1;
#pragma unroll
      for (int e = 0; e < 4; ++e) {
        v0[e] = w0[e] * dv0[e];
        v1[e] = w1[e] * dv1[e];
      }
      unsigned long long o0 = pk_fp8x4(v0), o1 = pk_fp8x4(v1);
      af_w[f * 8 + ks] = (long)((o1 << 32) | o0);
    }
  }
  __syncthreads();  // m2L + SB[0] staged, vectors visible

  long afX[16];  // wave's 32 xcov2 rows (fp8 A-frags, 2 groups)

  // ---------- phase 1: xcov2, 8 segments of 32 cols ----------
#pragma unroll
  for (int cp = 0; cp < 8; ++cp) {
    if (cp < 7 && w < 8) {
      int rl = w * 4 + (l >> 4);
      int c = l & 15;
      const unsigned char* src =
          m1f8t + (size_t)(cp + 1) * 8192 + rl * 256 + ((c ^ (rl & 7)) << 4);
      __builtin_amdgcn_global_load_lds(
          (const gas_u32*)src, (las_u32*)(SB[(cp + 1) & 1] + (w * 4) * 256), 16, 0, 0);
    }
    const unsigned char* sbc = SB[cp & 1];
    const int p = wc * 16 + lr;  // panel row = col within seg (wave's half)
    f32x4 acc0 = {0.f, 0.f, 0.f, 0.f};
    f32x4 acc1 = {0.f, 0.f, 0.f, 0.f};
#pragma unroll
    for (int ks = 0; ks < 8; ++ks) {
      long bq = PRD8(sbc, p, ks * 4 + lk);
      acc0 = __builtin_amdgcn_mfma_f32_16x16x32_fp8_fp8(af_w[ks], bq, acc0, 0, 0, 0);
      acc1 = __builtin_amdgcn_mfma_f32_16x16x32_fp8_fp8(af_w[8 + ks], bq, acc1, 0, 0, 0);
    }
    unsigned char* XP = XC + (cp & 1) * 8192;  // XB dbuf aliases XC head
    const int cc = cp * 32 + p;
    const float c2c = c2L[cc];
#pragma unroll
    for (int f = 0; f < 2; ++f) {
      int j0 = R32 + f * 16 + lk * 4;
      f32x4 ac = f ? acc1 : acc0;
      f32x4 st;
#pragma unroll
      for (int e = 0; e < 4; ++e) {
        int r = j0 + e;
        float g = ac[e];
        if (r == cc) g += s1L[r];
        float v = SQ2PI_F * c2L[r] * c2c * g;
        if (r == cc) v += d2pL[r];
        st[e] = v;
      }
      *(unsigned int*)(XP + SWZ32(p, j0)) = pk_fp8x4(st);
    }
    __syncthreads();
    if (cp == wr) {
#pragma unroll
      for (int ks = 0; ks < 8; ++ks) {
        afX[ks] = PRD8(XP, lr, ks * 4 + lk);
        afX[8 + ks] = PRD8(XP, 16 + lr, ks * 4 + lk);
      }
    }
  }
  __syncthreads();  // all afX pulls done before T3 overwrites XC head

  // ---------- T3: barrier-free; t3^T -> XC fp8 + fused diag ----------
#pragma unroll
  for (int lf = 0; lf < 8; ++lf) {
    const int p = wc * 128 + lf * 16 + lr;  // global t3 column
    f32x4 at0 = {0.f, 0.f, 0.f, 0.f};
    f32x4 at1 = {0.f, 0.f, 0.f, 0.f};
#pragma unroll
    for (int ks = 0; ks < 8; ++ks) {
      long bq = PRD8(m2L, p, ks * 4 + lk);
      at0 = __builtin_amdgcn_mfma_f32_16x16x32_fp8_fp8(afX[ks], bq, at0, 0, 0, 0);
      at1 = __builtin_amdgcn_mfma_f32_16x16x32_fp8_fp8(afX[8 + ks], bq, at1, 0, 0, 0);
    }
    const int j0 = R32 + lk * 4;
    *(unsigned int*)(XC + SWZ32(p, j0)) = pk_fp8x4(at0);
    *(unsigned int*)(XC + SWZ32(p, j0 + 16)) = pk_fp8x4(at1);
    // diag partial from resident m2L (pre-rounding f32 t3)
    f32x4 mv0 = upk_fp8x4(*(const unsigned int*)(m2L + SWZ32(p, j0)));
    f32x4 mv1 = upk_fp8x4(*(const unsigned int*)(m2L + SWZ32(p, j0 + 16)));
    float s = 0.f;
#pragma unroll
    for (int e = 0; e < 4; ++e) {
      s = fmaf(mv0[e], at0[e], s);
      s = fmaf(mv1[e], at1[e], s);
    }
    s += __shfl_xor(s, 16, 64);
    s += __shfl_xor(s, 32, 64);
    if (lk == 0) atomicAdd(&dsig[p], s);
  }
  __syncthreads();

  // ---------- c3 phase ----------
  if (tid < 256) {
    float ds = dsig[tid] + s2L[tid];
    float rs = rsqrtf(ds);
    float xb = tanhf(SQ2PI_F * h3bar[b * 256 + tid] * rs);
    x3bar[b * 256 + tid] = xb;
    float d = 1.f - xb * xb;
    c3L[tid] = d * rs;
    d3L[tid] = d;
  }
  __syncthreads();

  // ---------- SIG: barrier-free; sigma3 + fused epilogue -> d_out ----------
  long am2[16];
#pragma unroll
  for (int f = 0; f < 2; ++f)
#pragma unroll
    for (int ks = 0; ks < 8; ++ks)
      am2[f * 8 + ks] = PRD8(m2L, R32 + f * 16 + lr, ks * 4 + lk);

#pragma unroll
  for (int lf = 0; lf < 8; ++lf) {
    const int p = wc * 128 + lf * 16 + lr;  // output column
    f32x4 sc0 = {0.f, 0.f, 0.f, 0.f};
    f32x4 sc1 = {0.f, 0.f, 0.f, 0.f};
#pragma unroll
    for (int ks = 0; ks < 8; ++ks) {
      long bq = PRD8(XC, p, ks * 4 + lk);
      sc0 = __builtin_amdgcn_mfma_f32_16x16x32_fp8_fp8(am2[ks], bq, sc0, 0, 0, 0);
      sc1 = __builtin_amdgcn_mfma_f32_16x16x32_fp8_fp8(am2[8 + ks], bq, sc1, 0, 0, 0);
    }
    const int gl = p;
    const float cg = c3L[gl];
#pragma unroll
    for (int f = 0; f < 2; ++f) {
      int i0 = R32 + f * 16 + lk * 4;
      f32x4 sc = f ? sc1 : sc0;
      f32x4 st;
#pragma unroll
      for (int e = 0; e < 4; ++e) {
        int i = i0 + e;
        float g = sc[e];
        if (i == gl) g += s2L[i];
        float v = SQ2PI_F * c3L[i] * cg * g;
        if (i == gl) v += d3L[i];
        st[e] = v;
      }
      *(f32x4*)(xcov3 + ((size_t)b << 16) + (size_t)gl * 256 + i0) = st;
    }
  }
#undef PRD8
#undef SWZ32
}

// final layer + log_softmax + loss + frac_correct. grid 4 x block 64
__global__ void k_final4(const float* __restrict__ x3bar, const float* __restrict__ mlast,
                         const float* __restrict__ thlast, const int* __restrict__ target,
                         float* __restrict__ hlast_out, float* __restrict__ logp_out,
                         float* __restrict__ loss_out, float* __restrict__ frac_out) {
  __shared__ float Wl[2560];
  int t = threadIdx.x;
  int r = blockIdx.x * 64 + t;
  for (int p = t; p < 2560; p += 64) Wl[p] = mlast[p];
  __syncthreads();
  float acc[10];
#pragma unroll
  for (int c = 0; c < 10; ++c) acc[c] = thlast[c];
  for (int j = 0; j < 256; ++j) {
    float xv = x3bar[r * 256 + j];
#pragma unroll
    for (int c = 0; c < 10; ++c) acc[c] = fmaf(xv, Wl[j * 10 + c], acc[c]);
  }
#pragma unroll
  for (int c = 0; c < 10; ++c) hlast_out[r * 10 + c] = acc[c];
  float mx = acc[0];
  int am = 0;
#pragma unroll
  for (int c = 1; c < 10; ++c)
    if (acc[c] > mx) { mx = acc[c]; am = c; }
  float se = 0.f;
#pragma unroll
  for (int c = 0; c < 10; ++c) se += expf(acc[c] - mx);
  float lse = logf(se);
#pragma unroll
  for (int c = 0; c < 10; ++c) logp_out[r * 10 + c] = acc[c] - mx - lse;
  int tg = target[r];
  float lossc = -(acc[tg] - mx - lse) * (1.f / 256.f);
  float corr = (am == tg) ? (1.f / 256.f) : 0.f;
#pragma unroll
  for (int off = 32; off > 0; off >>= 1) {
    lossc += __shfl_down(lossc, off);
    corr += __shfl_down(corr, off);
  }
  if (t == 0) {
    atomicAdd(loss_out, lossc);
    atomicAdd(frac_out, corr);
  }
}

// ------------------------------------------------------------------

extern "C" void kernel_launch(void* const* d_in, const int* in_sizes, int n_in,
                              void* d_out, int out_size, void* d_ws, size_t ws_size,
                              hipStream_t stream) {
  const float* x = (const float*)d_in[0];
  const int* target = (const int*)d_in[1];
  const float* w0 = (const float*)d_in[2];
  const float* w1 = (const float*)d_in[3];
  const float* w2 = (const float*)d_in[4];
  const float* wlast = (const float*)d_in[5];
  const float* th0 = (const float*)d_in[6];
  const float* th1 = (const float*)d_in[7];
  const float* th2 = (const float*)d_in[8];
  const float* thlast = (const float*)d_in[9];

  float* W = (float*)d_ws;
  size_t o = 0;
  auto alloc = [&](size_t n) { float* p = W + o; o += n; return p; };
  float* m0 = alloc(200704);
  float* m1 = alloc(65536);
  float* m2 = alloc(65536);
  float* mlast = alloc(2560);
  float* s1 = alloc(256);
  float* s2 = alloc(256);
  float* d1 = alloc(65536);
  float* c2 = alloc(65536);
  float* d2p = alloc(65536);
  float* h3bar = alloc(65536);
  float* x3bar = alloc(65536);
  unsigned char* m1f8t = (unsigned char*)alloc(16384);  // 65536 fp8
  unsigned char* m2f8 = (unsigned char*)alloc(16384);   // 65536 fp8

  float* hlast = (float*)d_out;
  float* logp = hlast + 2560;
  float* xcov3_out = logp + 2560;
  float* loss = xcov3_out + 16777216;
  float* frac = loss + 1;

  // 1) prep (means + fp8 transposes + zero loss/frac)
  k_prep<<<1306, 256, 0, stream>>>(w0, w1, w2, wlast, m0, m1, m1f8t, m2, m2f8,
                                   mlast, loss);
  // 2) layers 1+2 (+h3) fused; x1bar stays in LDS
  k_layers<<<256, 512, 0, stream>>>(x, m0, m1, m2, th0, th1, th2, d1, c2, d2p,
                                    h3bar, s1, s2);
  // 3) fused sigma-chain (2 MFMA per ds_read, 2 indep chains, HW fp8 cvt)
  k_fused<<<256, 1024, 0, stream>>>(m1f8t, m2f8, d1, c2, d2p, s1, s2,
                                    h3bar, x3bar, xcov3_out);
  // 4) final layer + softmax + loss + acc
  k_final4<<<4, 64, 0, stream>>>(x3bar, mlast, thlast, target, hlast, logp, loss, frac);
}